// Round 4
// baseline (13452.657 us; speedup 1.0000x reference)
//
#include <hip/hip_runtime.h>
#include <cstdint>
#include <cstddef>

typedef __attribute__((ext_vector_type(8))) short bf16x8;
typedef __attribute__((ext_vector_type(4))) float f32x4;
#define DEVI __device__ __forceinline__

constexpr int B = 256, S = 128, V = 128, C = 16, H = 1024, Z = 256, NSTEP = 128;
constexpr int VC = V * C, G3 = 3 * H;
constexpr size_t BVC = (size_t)B * VC;

typedef __attribute__((address_space(1))) const unsigned short* gas_p;
typedef __attribute__((address_space(3))) unsigned short* las_p;

DEVI unsigned short f2bf(float f){unsigned u=__float_as_uint(f);u+=0x7fffu+((u>>16)&1u);return (unsigned short)(u>>16);}
DEVI float sigm(float x){return 1.f/(1.f+expf(-x));}
DEVI f32x4 MFMA(bf16x8 a,bf16x8 b,f32x4 c){return __builtin_amdgcn_mfma_f32_16x16x32_bf16(a,b,c,0,0,0);}
DEVI void stage16(const unsigned short* g, unsigned short* l){__builtin_amdgcn_global_load_lds((gas_p)g,(las_p)l,16,0,0);}

// ---- coherent (cross-XCD safe) access helpers ----
DEVI unsigned long long ldc8(const void* p){return __hip_atomic_load((const unsigned long long*)p,__ATOMIC_RELAXED,__HIP_MEMORY_SCOPE_AGENT);}
DEVI void stc8(void* p, unsigned long long v){__hip_atomic_store((unsigned long long*)p,v,__ATOMIC_RELAXED,__HIP_MEMORY_SCOPE_AGENT);}
DEVI unsigned ldc4(const void* p){return __hip_atomic_load((const unsigned*)p,__ATOMIC_RELAXED,__HIP_MEMORY_SCOPE_AGENT);}
DEVI void stc4(void* p, unsigned v){__hip_atomic_store((unsigned*)p,v,__ATOMIC_RELAXED,__HIP_MEMORY_SCOPE_AGENT);}
DEVI bf16x8 ldfragc(const unsigned short* p){
  union{bf16x8 v;unsigned long long q[2];}u;
  u.q[0]=ldc8(p); u.q[1]=ldc8(p+4); return u.v;
}
DEVI unsigned long long pack4(float a,float b,float c,float d){
  return (unsigned long long)f2bf(a)|((unsigned long long)f2bf(b)<<16)|((unsigned long long)f2bf(c)<<32)|((unsigned long long)f2bf(d)<<48);
}
DEVI unsigned long long packf2(float a,float b){
  return (unsigned long long)__float_as_uint(a)|((unsigned long long)__float_as_uint(b)<<32);
}

// ---- counted waits (compile-time n) ----
DEVI void wv(int n){
  if(n==0)      asm volatile("s_waitcnt vmcnt(0)":::"memory");
  else if(n==4) asm volatile("s_waitcnt vmcnt(4)":::"memory");
  else if(n==8) asm volatile("s_waitcnt vmcnt(8)":::"memory");
  else if(n==10)asm volatile("s_waitcnt vmcnt(10)":::"memory");
  else if(n==12)asm volatile("s_waitcnt vmcnt(12)":::"memory");
  else if(n==16)asm volatile("s_waitcnt vmcnt(16)":::"memory");
  else if(n==20)asm volatile("s_waitcnt vmcnt(20)":::"memory");
}
DEVI void lg0(){asm volatile("s_waitcnt lgkmcnt(0)":::"memory");}
DEVI void cmb(){asm volatile("" ::: "memory");}
DEVI void drain_sync(){asm volatile("s_waitcnt vmcnt(0) lgkmcnt(0)":::"memory");__syncthreads();}

// ---- flat fire-and-forget grid barrier ----
DEVI void arrive(unsigned* c){ if(threadIdx.x==0)__hip_atomic_fetch_add(c,1u,__ATOMIC_RELAXED,__HIP_MEMORY_SCOPE_AGENT);}
DEVI void waitbar(unsigned* c,unsigned tgt){
  if(threadIdx.x==0){
    while(__hip_atomic_load(c,__ATOMIC_RELAXED,__HIP_MEMORY_SCOPE_AGENT)<tgt)__builtin_amdgcn_s_sleep(1);
  }
  __syncthreads();
}

// h-fragment (coherent) load pair for one kt
#define LDHD(SRC,KT,Ha,Hb) { (Ha)=ldfragc((SRC)+(size_t)mrow*H+((KT)<<6)+(l4<<3)); (Hb)=ldfragc((SRC)+(size_t)mrow*H+((KT)<<6)+((4+l4)<<3)); cmb(); }

// ---------------- prep kernels ----------------
__global__ void k_cvt(const float* __restrict__ src, unsigned short* __restrict__ dst, int n){
  for (int i=blockIdx.x*256+threadIdx.x;i<n;i+=gridDim.x*256) dst[i]=f2bf(src[i]);
}

__global__ void k_xt(const float* __restrict__ x, unsigned short* __restrict__ xtb){
  __shared__ float tile[32][33];
  int sb=blockIdx.x*32, rb=blockIdx.y*32, tx=threadIdx.x, ty=threadIdx.y;
  for (int i=ty;i<32;i+=8) tile[i][tx]=x[(size_t)(rb+i)*S+sb+tx];
  __syncthreads();
  for (int i=ty;i<32;i+=8) xtb[(size_t)(sb+i)*(B*V)+rb+tx]=f2bf(tile[tx][i]);
}

__global__ void k_wt(const float* __restrict__ w, float* __restrict__ wt){
  __shared__ float tile[32][33];
  int vb=blockIdx.x*32, nb=blockIdx.y*32, tx=threadIdx.x, ty=threadIdx.y;
  for (int i=ty;i<32;i+=8) tile[i][tx]=w[(size_t)(nb+i)*(VC+Z)+vb+tx];
  __syncthreads();
  for (int i=ty;i<32;i+=8) wt[(size_t)(vb+i)*G3+nb+tx]=tile[tx][i];
}

__global__ __launch_bounds__(256) void k_mu_var_z(const float* __restrict__ hf,const float* __restrict__ hb,
    const float* __restrict__ Wmu,const float* __restrict__ bmu,
    const float* __restrict__ Wvar,const float* __restrict__ bvar,
    const float* __restrict__ noise,
    float* __restrict__ omu,float* __restrict__ ovar,float* __restrict__ oz,float* __restrict__ zws){
  __shared__ float e[2*H];
  int b=blockIdx.x, t=threadIdx.x;
  for (int i=0;i<2*H/256;++i){int k=t+i*256; e[k]=(k<H)?hf[b*H+k]:hb[b*H+k-H];}
  __syncthreads();
  const float* wm=Wmu+(size_t)t*2*H; const float* wv2=Wvar+(size_t)t*2*H;
  float am=bmu[t], av=bvar[t];
  for (int k=0;k<2*H;++k){am+=e[k]*wm[k];av+=e[k]*wv2[k];}
  float vv=expf(av), zz=am+vv*noise[b*Z+t];
  omu[b*Z+t]=am; ovar[b*Z+t]=vv; oz[b*Z+t]=zz; zws[b*Z+t]=zz;
}

__global__ void k_zpart(const float* __restrict__ z,const float* __restrict__ c1Wih,
                        const float* __restrict__ bih,float* __restrict__ zpart){
  int idx=blockIdx.x*256+threadIdx.x;
  int b=idx/G3, n=idx%G3;
  const float* w=c1Wih+(size_t)n*(VC+Z)+VC;
  const float* zr=z+b*Z;
  float a=bih[n];
  for (int k=0;k<Z;++k) a+=zr[k]*w[k];
  zpart[idx]=a;
}

__global__ void k_h1init(const float* __restrict__ z,const float* __restrict__ Winit,
                         const float* __restrict__ binit,
                         float* __restrict__ h1f,unsigned short* __restrict__ h1b,int* __restrict__ idxb){
  int idx=blockIdx.x*256+threadIdx.x;
  int b=idx>>10, jj=idx&(H-1);
  const float* w=Winit+(size_t)jj*Z;
  const float* zr=z+b*Z;
  float a=binit[jj];
  for (int k=0;k<Z;++k) a+=zr[k]*w[k];
  float t=tanhf(a);
  h1f[idx]=t; h1b[idx]=f2bf(t);
  if (idx<B) idxb[idx]=VC-1;
}

// ---------------- persistent encoder (256 blocks) ----------------
struct EncP {
  const unsigned short *xtb,*wihf,*whhf,*wihb,*whhb;
  const float *bihf,*bhhf,*bihb,*bhhb;
  unsigned short *hf0,*hf1,*hb0,*hb1;
  float *hf,*hb;
  unsigned* bar;
};

#define ENC_MM(DB,H0,H1) { const unsigned short* bb=lw+(DB)*6144; \
  _Pragma("unroll") for (int kf=0;kf<2;++kf){ \
    const int sw=(((kf<<2)+l4)^(l15&7))<<3; \
    bf16x8 hh=kf?(H1):(H0); \
    _Pragma("unroll") for (int nj=0;nj<2;++nj){ \
      const int ro=((nj<<4)+l15)*64+sw; \
      bf16x8 w0=*(const bf16x8*)&bb[ro]; \
      bf16x8 w1=*(const bf16x8*)&bb[2048+ro]; \
      bf16x8 w2=*(const bf16x8*)&bb[4096+ro]; \
      aR[nj]=MFMA(w0,hh,aR[nj]); aZ[nj]=MFMA(w1,hh,aZ[nj]); aNH[nj]=MFMA(w2,hh,aNH[nj]); } } }

#define ENC_MMX(DB,XKT) { const unsigned short* bb=lw+(DB)*6144; \
  _Pragma("unroll") for (int kf=0;kf<2;++kf){ \
    const int ch=(kf<<2)+l4; const int sw=(ch^(l15&7))<<3; \
    bf16x8 hh=*(const bf16x8*)&P.xtb[(size_t)xs*(B*V)+(size_t)mrow*V+((XKT)<<6)+(ch<<3)]; \
    _Pragma("unroll") for (int nj=0;nj<2;++nj){ \
      const int ro=((nj<<4)+l15)*64+sw; \
      bf16x8 w0=*(const bf16x8*)&bb[ro]; \
      bf16x8 w1=*(const bf16x8*)&bb[2048+ro]; \
      bf16x8 w2=*(const bf16x8*)&bb[4096+ro]; \
      aR[nj]=MFMA(w0,hh,aR[nj]); aZ[nj]=MFMA(w1,hh,aZ[nj]); aNX[nj]=MFMA(w2,hh,aNX[nj]); } } }

__global__ __launch_bounds__(256,1) void k_enc(EncP P){
  __shared__ unsigned short lws[49152];
  const int tid=threadIdx.x, wave=tid>>6, lane=tid&63;
  const int l15=lane&15, l4=lane>>4, l8r=lane>>3, l8c=lane&7;
  const int bid=blockIdx.x, xcd=bid&7, q=bid>>3;
  const int dir=q>>4, q2=q&15, jt=(q2&1)*8+xcd, mt=q2>>1;
  const int wm=(wave&1)*16, wn=(wave>>1)*32;
  const unsigned short* wih=dir?P.wihb:P.wihf;
  const unsigned short* whh=dir?P.whhb:P.whhf;
  const float* bih=dir?P.bihb:P.bihf;
  const float* bhh=dir?P.bhhb:P.bhhf;
  unsigned short* hbuf[2]={dir?P.hb0:P.hf0, dir?P.hb1:P.hf1};
  unsigned short* lw=&lws[wave*12288];
  const int mrow=mt*32+wm+l15;

  f32x4 biR[2],biZ[2],biN[2],bhR[2],bhZ[2],bhN[2];
#pragma unroll
  for (int nj=0;nj<2;++nj){
    int j0=jt*64+wn+nj*16+(l4<<2);
    biR[nj]=*(const f32x4*)&bih[j0]; biZ[nj]=*(const f32x4*)&bih[H+j0]; biN[nj]=*(const f32x4*)&bih[2*H+j0];
    bhR[nj]=*(const f32x4*)&bhh[j0]; bhZ[nj]=*(const f32x4*)&bhh[H+j0]; bhN[nj]=*(const f32x4*)&bhh[2*H+j0];
  }
  float hreg[2][4]={};

  auto Wh=[&](int kt,int db){
    unsigned short* d=lw+db*6144;
#pragma unroll
    for (int g=0;g<3;++g)
#pragma unroll
      for (int i=0;i<4;++i)
        stage16(whh+(size_t)((g<<10)+jt*64+wn+i*8+l8r)*H+(kt<<6)+((l8c^l8r)<<3), d+(g*32+i*8)*64);
    cmb();
  };
  auto Wx=[&](int kt,int db){
    unsigned short* d=lw+db*6144;
#pragma unroll
    for (int g=0;g<3;++g)
#pragma unroll
      for (int i=0;i<4;++i)
        stage16(wih+(size_t)((g<<10)+jt*64+wn+i*8+l8r)*V+(kt<<6)+((l8c^l8r)<<3), d+(g*32+i*8)*64);
    cmb();
  };

  Wh(0,0); Wh(1,1);   // initial prefetch

  for (int s=0;s<S;++s){
    const unsigned short* hsrc=hbuf[s&1];
    unsigned short* hdst=hbuf[(s+1)&1];
    const int xs=dir?(S-1-s):s;
    bf16x8 hA0,hA1,hB0,hB1;
    f32x4 aR[2]={},aZ[2]={},aNH[2]={},aNX[2]={};
    LDHD(hsrc,0,hA0,hA1); LDHD(hsrc,1,hB0,hB1);
    wv(4);  ENC_MM(0,hA0,hA1); lg0(); Wh(2,0); LDHD(hsrc,2,hA0,hA1);
    for (int i=0;i<6;++i){
      wv(16); ENC_MM(1,hB0,hB1); lg0(); Wh(2*i+3,1); LDHD(hsrc,2*i+3,hB0,hB1);
      wv(16); ENC_MM(0,hA0,hA1); lg0(); Wh(2*i+4,0); LDHD(hsrc,2*i+4,hA0,hA1);
    }
    wv(16); ENC_MM(1,hB0,hB1); lg0(); Wh(15,1); LDHD(hsrc,15,hB0,hB1);
    wv(16); ENC_MM(0,hA0,hA1); lg0(); Wx(0,0);
    wv(12); ENC_MM(1,hB0,hB1); lg0(); Wx(1,1);
    wv(12); ENC_MMX(0,0); lg0();
    wv(0);  ENC_MMX(1,1); lg0();
    // fused GRU combine (h in registers; publish bf16 coherently)
#pragma unroll
    for (int nj=0;nj<2;++nj){
      int j0=jt*64+wn+nj*16+(l4<<2);
      float hv[4];
#pragma unroll
      for (int r=0;r<4;++r){
        float rg=sigm(aR[nj][r]+biR[nj][r]+bhR[nj][r]);
        float zg=sigm(aZ[nj][r]+biZ[nj][r]+bhZ[nj][r]);
        float nn=tanhf(aNX[nj][r]+biN[nj][r]+rg*(aNH[nj][r]+bhN[nj][r]));
        float hnew=(1.f-zg)*nn+zg*hreg[nj][r];
        hreg[nj][r]=hnew; hv[r]=hnew;
      }
      stc8(hdst+(size_t)mrow*H+j0, pack4(hv[0],hv[1],hv[2],hv[3]));
    }
    drain_sync();
    arrive(P.bar);
    Wh(0,0); Wh(1,1);                 // prefetch next step during poll
    waitbar(P.bar,256u*(unsigned)(s+1));
  }
  float* hout=dir?P.hb:P.hf;
#pragma unroll
  for (int nj=0;nj<2;++nj){
    int j0=jt*64+wn+nj*16+(l4<<2);
    f32x4 v; v[0]=hreg[nj][0];v[1]=hreg[nj][1];v[2]=hreg[nj][2];v[3]=hreg[nj][3];
    *(f32x4*)&hout[(size_t)mrow*H+j0]=v;
  }
}

// ---------------- persistent decoder (256 blocks) ----------------
struct DecP {
  unsigned short *h1b0,*h1b1,*h2b0,*h2b1;
  const unsigned short *w1hh,*w2ih,*w2hh,*wout;
  const float *bhh1,*bih2,*bhh2,*bout;
  const float *zpart,*WT,*h1f;
  float *logits,*lsbuf,*recon;
  int* idxb;
  unsigned* bar;
};

#define MM1(DB,H0,H1) { const unsigned short* bb=lw+(DB)*3072; \
  _Pragma("unroll") for (int kf=0;kf<2;++kf){ \
    const int sw=(((kf<<2)+l4)^(l15&7))<<3; const int ro=l15*64+sw; \
    bf16x8 w0=*(const bf16x8*)&bb[ro]; bf16x8 w1=*(const bf16x8*)&bb[1024+ro]; bf16x8 w2=*(const bf16x8*)&bb[2048+ro]; \
    bf16x8 hh=kf?(H1):(H0); \
    aR=MFMA(w0,hh,aR); aZ=MFMA(w1,hh,aZ); aN=MFMA(w2,hh,aN); } }

#define MM2(DB,A10,A11,A20,A21) { const unsigned short* bb=lw+(DB)*6144; \
  _Pragma("unroll") for (int kf=0;kf<2;++kf){ \
    const int sw=(((kf<<2)+l4)^(l15&7))<<3; const int ro=l15*64+sw; \
    bf16x8 wi0=*(const bf16x8*)&bb[ro];      bf16x8 wi1=*(const bf16x8*)&bb[1024+ro]; bf16x8 wi2=*(const bf16x8*)&bb[2048+ro]; \
    bf16x8 wh0=*(const bf16x8*)&bb[3072+ro]; bf16x8 wh1=*(const bf16x8*)&bb[4096+ro]; bf16x8 wh2=*(const bf16x8*)&bb[5120+ro]; \
    bf16x8 a1=kf?(A11):(A10), a2=kf?(A21):(A20); \
    aR=MFMA(wi0,a1,aR); aR=MFMA(wh0,a2,aR); \
    aZ=MFMA(wi1,a1,aZ); aZ=MFMA(wh1,a2,aZ); \
    aNI=MFMA(wi2,a1,aNI); aNH=MFMA(wh2,a2,aNH); } }

#define MM3(DB,H0,H1) { const unsigned short* bb=lw+(DB)*2048; \
  _Pragma("unroll") for (int kf=0;kf<2;++kf){ \
    const int sw=(((kf<<2)+l4)^(l15&7))<<3; \
    bf16x8 w0=*(const bf16x8*)&bb[l15*64+sw]; bf16x8 w1=*(const bf16x8*)&bb[(16+l15)*64+sw]; \
    bf16x8 hh=kf?(H1):(H0); \
    ac0=MFMA(w0,hh,ac0); ac1=MFMA(w1,hh,ac1); } }

__global__ __launch_bounds__(256,1) void k_dec(DecP P){
  __shared__ unsigned short lws[49152];
  __shared__ float sm_ls[VC];
  __shared__ float sm_rv[256];
  __shared__ int   sm_ri[256];
  const int tid=threadIdx.x, wave=tid>>6, lane=tid&63;
  const int l15=lane&15, l4=lane>>4, l8r=lane>>3, l8c=lane&7;
  const int bid=blockIdx.x, xcd=bid&7, q=bid>>3;
  const int jt=(q&3)*8+xcd, mt=q>>2;
  const int wm=(wave&1)*16, wn=(wave>>1)*16;
  const int wn3=(wave>>1)*32;
  unsigned short* lw=&lws[wave*12288];
  unsigned short* h1b[2]={P.h1b0,P.h1b1};
  unsigned short* h2b[2]={P.h2b0,P.h2b1};
  const int mrow=mt*32+wm+l15;
  const int j0=jt*32+wn+(l4<<2);

  // hoisted step-invariants
  f32x4 zR4=*(const f32x4*)&P.zpart[(size_t)mrow*G3+j0];
  f32x4 zZ4=*(const f32x4*)&P.zpart[(size_t)mrow*G3+H+j0];
  f32x4 zN4=*(const f32x4*)&P.zpart[(size_t)mrow*G3+2*H+j0];
  f32x4 b1R=*(const f32x4*)&P.bhh1[j0], b1Z=*(const f32x4*)&P.bhh1[H+j0], b1N=*(const f32x4*)&P.bhh1[2*H+j0];
  f32x4 c2Rv,c2Zv,biN2,bhN2;
  { f32x4 a=*(const f32x4*)&P.bih2[j0],   b2=*(const f32x4*)&P.bhh2[j0];   c2Rv=a+b2; }
  { f32x4 a=*(const f32x4*)&P.bih2[H+j0], b2=*(const f32x4*)&P.bhh2[H+j0]; c2Zv=a+b2; }
  biN2=*(const f32x4*)&P.bih2[2*H+j0]; bhN2=*(const f32x4*)&P.bhh2[2*H+j0];
  f32x4 bo0=*(const f32x4*)&P.bout[jt*64+wn3+(l4<<2)];
  f32x4 bo1=*(const f32x4*)&P.bout[jt*64+wn3+16+(l4<<2)];
  f32x4 h1i=*(const f32x4*)&P.h1f[(size_t)mrow*H+j0];
  float h1reg[4]={h1i[0],h1i[1],h1i[2],h1i[3]};
  float h2reg[4]={};

  auto W1i=[&](int kt,int db){
    unsigned short* d=lw+db*3072;
#pragma unroll
    for (int g=0;g<3;++g)
#pragma unroll
      for (int i=0;i<2;++i)
        stage16(P.w1hh+(size_t)((g<<10)+jt*32+wn+i*8+l8r)*H+(kt<<6)+((l8c^l8r)<<3), d+(g*16+i*8)*64);
    cmb();
  };
  auto W2i=[&](int kt,int db){
    unsigned short* d=lw+db*6144;
#pragma unroll
    for (int m=0;m<6;++m){
      const unsigned short* src=(m<3)?P.w2ih:P.w2hh;
      const int g=(m<3)?m:(m-3);
#pragma unroll
      for (int i=0;i<2;++i)
        stage16(src+(size_t)((g<<10)+jt*32+wn+i*8+l8r)*H+(kt<<6)+((l8c^l8r)<<3), d+(m*16+i*8)*64);
    }
    cmb();
  };
  auto W3i=[&](int kt,int db){
    unsigned short* d=lw+db*2048;
#pragma unroll
    for (int i=0;i<4;++i)
      stage16(P.wout+(size_t)(jt*64+wn3+i*8+l8r)*H+(kt<<6)+((l8c^l8r)<<3), d+i*8*64);
    cmb();
  };

  unsigned ph=0;
  W1i(0,0); W1i(1,1);   // initial prefetch

  for (int t=0;t<NSTEP;++t){
    const int cur=t&1, nxt=cur^1;
    // ---------- stage1: gh1 GEMM + fused combine1 ----------
    {
      const unsigned short* h1src=h1b[cur];
      int idxm=(int)ldc4(&P.idxb[mrow]);
      bf16x8 hA0,hA1,hB0,hB1;
      f32x4 aR={},aZ={},aN={};
      LDHD(h1src,0,hA0,hA1); LDHD(h1src,1,hB0,hB1);
      wv(4);  MM1(0,hA0,hA1); lg0(); W1i(2,0); LDHD(h1src,2,hA0,hA1);
      for (int i=0;i<6;++i){
        wv(10); MM1(1,hB0,hB1); lg0(); W1i(2*i+3,1); LDHD(h1src,2*i+3,hB0,hB1);
        wv(10); MM1(0,hA0,hA1); lg0(); W1i(2*i+4,0); LDHD(h1src,2*i+4,hA0,hA1);
      }
      wv(10); MM1(1,hB0,hB1); lg0(); W1i(15,1); LDHD(h1src,15,hB0,hB1);
      wv(10); MM1(0,hA0,hA1); lg0();
      wv(0);  MM1(1,hB0,hB1); lg0();
      const float* wtr=P.WT+(size_t)idxm*G3;
      f32x4 wR=*(const f32x4*)&wtr[j0], wZ=*(const f32x4*)&wtr[H+j0], wN=*(const f32x4*)&wtr[2*H+j0];
      float hv[4];
#pragma unroll
      for (int r=0;r<4;++r){
        float rg=sigm(zR4[r]+wR[r]+aR[r]+b1R[r]);
        float zg=sigm(zZ4[r]+wZ[r]+aZ[r]+b1Z[r]);
        float nn=tanhf(zN4[r]+wN[r]+rg*(aN[r]+b1N[r]));
        float hnew=(1.f-zg)*nn+zg*h1reg[r];
        h1reg[r]=hnew; hv[r]=hnew;
      }
      stc8(h1b[nxt]+(size_t)mrow*H+j0, pack4(hv[0],hv[1],hv[2],hv[3]));
    }
    drain_sync(); ++ph; arrive(P.bar);
    W2i(0,0); W2i(1,1);
    waitbar(P.bar,256u*ph);
    // ---------- stage2: gi2+gh2 GEMM + fused combine2 ----------
    {
      const unsigned short* s1=h1b[nxt];
      const unsigned short* s2=(t==0)?h1b[nxt]:h2b[cur];
      bf16x8 xA0,xA1,yA0,yA1,xB0,xB1,yB0,yB1;
      f32x4 aR={},aZ={},aNI={},aNH={};
      LDHD(s1,0,xA0,xA1); LDHD(s2,0,yA0,yA1); LDHD(s1,1,xB0,xB1); LDHD(s2,1,yB0,yB1);
      wv(8);  MM2(0,xA0,xA1,yA0,yA1); lg0(); W2i(2,0); LDHD(s1,2,xA0,xA1); LDHD(s2,2,yA0,yA1);
      for (int i=0;i<6;++i){
        wv(20); MM2(1,xB0,xB1,yB0,yB1); lg0(); W2i(2*i+3,1); LDHD(s1,2*i+3,xB0,xB1); LDHD(s2,2*i+3,yB0,yB1);
        wv(20); MM2(0,xA0,xA1,yA0,yA1); lg0(); W2i(2*i+4,0); LDHD(s1,2*i+4,xA0,xA1); LDHD(s2,2*i+4,yA0,yA1);
      }
      wv(20); MM2(1,xB0,xB1,yB0,yB1); lg0(); W2i(15,1); LDHD(s1,15,xB0,xB1); LDHD(s2,15,yB0,yB1);
      wv(20); MM2(0,xA0,xA1,yA0,yA1); lg0();
      wv(0);  MM2(1,xB0,xB1,yB0,yB1); lg0();
      float hv[4];
#pragma unroll
      for (int r=0;r<4;++r){
        float rg=sigm(aR[r]+c2Rv[r]);
        float zg=sigm(aZ[r]+c2Zv[r]);
        float nn=tanhf(aNI[r]+biN2[r]+rg*(aNH[r]+bhN2[r]));
        float hp=(t==0)?h1reg[r]:h2reg[r];
        float hnew=(1.f-zg)*nn+zg*hp;
        h2reg[r]=hnew; hv[r]=hnew;
      }
      stc8(h2b[nxt]+(size_t)mrow*H+j0, pack4(hv[0],hv[1],hv[2],hv[3]));
    }
    drain_sync(); ++ph; arrive(P.bar);
    W3i(0,0); W3i(1,1);
    waitbar(P.bar,256u*ph);
    // ---------- stage3: logits GEMM ----------
    {
      const unsigned short* hs=h2b[nxt];
      bf16x8 hA0,hA1,hB0,hB1;
      f32x4 ac0={},ac1={};
      LDHD(hs,0,hA0,hA1); LDHD(hs,1,hB0,hB1);
      wv(4); MM3(0,hA0,hA1); lg0(); W3i(2,0); LDHD(hs,2,hA0,hA1);
      for (int i=0;i<6;++i){
        wv(8); MM3(1,hB0,hB1); lg0(); W3i(2*i+3,1); LDHD(hs,2*i+3,hB0,hB1);
        wv(8); MM3(0,hA0,hA1); lg0(); W3i(2*i+4,0); LDHD(hs,2*i+4,hA0,hA1);
      }
      wv(8); MM3(1,hB0,hB1); lg0(); W3i(15,1); LDHD(hs,15,hB0,hB1);
      wv(8); MM3(0,hA0,hA1); lg0();
      wv(0); MM3(1,hB0,hB1); lg0();
      int n0=jt*64+wn3+(l4<<2);
      stc8(&P.logits[(size_t)mrow*VC+n0],    packf2(ac0[0]+bo0[0],ac0[1]+bo0[1]));
      stc8(&P.logits[(size_t)mrow*VC+n0+2],  packf2(ac0[2]+bo0[2],ac0[3]+bo0[3]));
      stc8(&P.logits[(size_t)mrow*VC+n0+16], packf2(ac1[0]+bo1[0],ac1[1]+bo1[1]));
      stc8(&P.logits[(size_t)mrow*VC+n0+18], packf2(ac1[2]+bo1[2],ac1[3]+bo1[3]));
    }
    drain_sync(); ++ph; arrive(P.bar);
    waitbar(P.bar,256u*ph);
    // ---------- stage4: log-softmax + argmax (block = batch row) ----------
    {
      const int b=bid;
#pragma unroll
      for (int i=0;i<4;++i){
        unsigned long long qq=ldc8(&P.logits[(size_t)b*VC+tid*8+i*2]);
        sm_ls[tid*8+i*2]  =__uint_as_float((unsigned)qq);
        sm_ls[tid*8+i*2+1]=__uint_as_float((unsigned)(qq>>32));
      }
      __syncthreads();
      if (tid<V){
        float mx=-1e30f;
        for (int c=0;c<C;++c) mx=fmaxf(mx,sm_ls[c*V+tid]);
        float sum=0.f;
        for (int c=0;c<C;++c) sum+=expf(sm_ls[c*V+tid]-mx);
        float lse=mx+logf(sum);
        for (int c=0;c<C;++c) sm_ls[c*V+tid]-=lse;
      }
      __syncthreads();
      float bv=-1e30f; int bi=0;
#pragma unroll
      for (int i=0;i<VC/256;++i){
        int n=i*256+tid; float v=sm_ls[n];
        if (v>bv){bv=v;bi=n;}
      }
      sm_rv[tid]=bv; sm_ri[tid]=bi;
      __syncthreads();
      for (int s2=128;s2>0;s2>>=1){
        if (tid<s2){
          float v2=sm_rv[tid+s2]; int i2=sm_ri[tid+s2];
          if (v2>sm_rv[tid]||(v2==sm_rv[tid]&&i2<sm_ri[tid])){sm_rv[tid]=v2;sm_ri[tid]=i2;}
        }
        __syncthreads();
      }
      if (tid==0) stc4(&P.idxb[b],(unsigned)sm_ri[0]);
      float* dst=P.lsbuf+(size_t)(t&15)*BVC+(size_t)b*VC;
#pragma unroll
      for (int i=0;i<4;++i)
        stc8(&dst[tid*8+i*2], packf2(sm_ls[tid*8+i*2],sm_ls[tid*8+i*2+1]));
    }
    drain_sync(); ++ph; arrive(P.bar);
    W1i(0,0); W1i(1,1);
    waitbar(P.bar,256u*ph);
    // ---------- flush 16 staged steps -> recon ----------
    if ((t&15)==15){
      const int t0=t-15;
      const size_t e0=((size_t)bid*256+tid)*8;
#pragma unroll
      for (int pe=0;pe<4;++pe){
        float va[16],vb[16];
#pragma unroll
        for (int j2=0;j2<16;++j2){
          unsigned long long qq=ldc8(&P.lsbuf[(size_t)j2*BVC+e0+pe*2]);
          va[j2]=__uint_as_float((unsigned)qq); vb[j2]=__uint_as_float((unsigned)(qq>>32));
        }
        float* d0=&P.recon[(e0+pe*2)*NSTEP+t0];
        float* d1=&P.recon[(e0+pe*2+1)*NSTEP+t0];
#pragma unroll
        for (int k=0;k<16;++k){ d0[k]=va[k]; d1[k]=vb[k]; }
      }
    }
  }
}

// ---------------- host orchestration ----------------
extern "C" void kernel_launch(void* const* d_in, const int* in_sizes, int n_in,
                              void* d_out, int out_size, void* d_ws, size_t ws_size,
                              hipStream_t stream) {
  const float* x        = (const float*)d_in[0];
  const float* noise    = (const float*)d_in[1];
  const float* gruf_Wih = (const float*)d_in[2];
  const float* gruf_Whh = (const float*)d_in[3];
  const float* gruf_bih = (const float*)d_in[4];
  const float* gruf_bhh = (const float*)d_in[5];
  const float* grub_Wih = (const float*)d_in[6];
  const float* grub_Whh = (const float*)d_in[7];
  const float* grub_bih = (const float*)d_in[8];
  const float* grub_bhh = (const float*)d_in[9];
  const float* Wmu      = (const float*)d_in[10];
  const float* bmu      = (const float*)d_in[11];
  const float* Wvar     = (const float*)d_in[12];
  const float* bvar     = (const float*)d_in[13];
  const float* Winit    = (const float*)d_in[14];
  const float* binit    = (const float*)d_in[15];
  const float* c1_Wih   = (const float*)d_in[16];
  const float* c1_Whh   = (const float*)d_in[17];
  const float* c1_bih   = (const float*)d_in[18];
  const float* c1_bhh   = (const float*)d_in[19];
  const float* c2_Wih   = (const float*)d_in[20];
  const float* c2_Whh   = (const float*)d_in[21];
  const float* c2_bih   = (const float*)d_in[22];
  const float* c2_bhh   = (const float*)d_in[23];
  const float* Wout     = (const float*)d_in[24];
  const float* bout     = (const float*)d_in[25];

  float* omu = (float*)d_out;
  float* ovar = omu + B*Z;
  float* oz = ovar + B*Z;
  float* orecon = oz + B*Z;

  char* p = (char*)d_ws;
  auto carve = [&](size_t bytes){ char* r = p; p += (bytes+255)&~(size_t)255; return r; };
  unsigned short* wihf_b  = (unsigned short*)carve((size_t)G3*V*2);
  unsigned short* whhf_b  = (unsigned short*)carve((size_t)G3*H*2);
  unsigned short* wihb_b  = (unsigned short*)carve((size_t)G3*V*2);
  unsigned short* whhb_b  = (unsigned short*)carve((size_t)G3*H*2);
  unsigned short* wc1hh_b = (unsigned short*)carve((size_t)G3*H*2);
  unsigned short* wc2ih_b = (unsigned short*)carve((size_t)G3*H*2);
  unsigned short* wc2hh_b = (unsigned short*)carve((size_t)G3*H*2);
  unsigned short* wout_b  = (unsigned short*)carve((size_t)VC*H*2);
  unsigned short* xtb     = (unsigned short*)carve((size_t)S*B*V*2);
  unsigned short* hf0     = (unsigned short*)carve((size_t)B*H*2);
  unsigned short* hf1     = (unsigned short*)carve((size_t)B*H*2);
  unsigned short* hb0     = (unsigned short*)carve((size_t)B*H*2);
  unsigned short* hb1     = (unsigned short*)carve((size_t)B*H*2);
  unsigned short* h1b0    = (unsigned short*)carve((size_t)B*H*2);
  unsigned short* h1b1    = (unsigned short*)carve((size_t)B*H*2);
  unsigned short* h2b0    = (unsigned short*)carve((size_t)B*H*2);
  unsigned short* h2b1    = (unsigned short*)carve((size_t)B*H*2);
  float* WT     = (float*)carve((size_t)VC*G3*4);
  float* zpart  = (float*)carve((size_t)B*G3*4);
  float* hf     = (float*)carve((size_t)B*H*4);
  float* hb     = (float*)carve((size_t)B*H*4);
  float* h1f    = (float*)carve((size_t)B*H*4);
  float* zws    = (float*)carve((size_t)B*Z*4);
  float* logits = (float*)carve((size_t)B*VC*4);
  float* lsbuf  = (float*)carve((size_t)16*BVC*4);
  int* idxb     = (int*)carve((size_t)B*4);
  unsigned* barE= (unsigned*)carve(256);
  unsigned* barD= (unsigned*)carve(256);

  dim3 blk(256);
  auto cvt=[&](const float* s, unsigned short* d, int n){
    int nb=(n+255)/256; if (nb>2048) nb=2048;
    k_cvt<<<nb,blk,0,stream>>>(s,d,n);
  };
  cvt(gruf_Wih,wihf_b,G3*V);
  cvt(gruf_Whh,whhf_b,G3*H);
  cvt(grub_Wih,wihb_b,G3*V);
  cvt(grub_Whh,whhb_b,G3*H);
  cvt(c1_Whh,wc1hh_b,G3*H);
  cvt(c2_Wih,wc2ih_b,G3*H);
  cvt(c2_Whh,wc2hh_b,G3*H);
  cvt(Wout,wout_b,VC*H);
  k_xt<<<dim3(S/32,(B*V)/32),dim3(32,8),0,stream>>>(x,xtb);
  k_wt<<<dim3(VC/32,G3/32),dim3(32,8),0,stream>>>(c1_Wih,WT);
  hipMemsetAsync(hf0,0,(size_t)B*H*2,stream);
  hipMemsetAsync(hb0,0,(size_t)B*H*2,stream);
  hipMemsetAsync(barE,0,256,stream);
  hipMemsetAsync(barD,0,256,stream);

  EncP ep;
  ep.xtb=xtb; ep.wihf=wihf_b; ep.whhf=whhf_b; ep.wihb=wihb_b; ep.whhb=whhb_b;
  ep.bihf=gruf_bih; ep.bhhf=gruf_bhh; ep.bihb=grub_bih; ep.bhhb=grub_bhh;
  ep.hf0=hf0; ep.hf1=hf1; ep.hb0=hb0; ep.hb1=hb1;
  ep.hf=hf; ep.hb=hb; ep.bar=barE;
  k_enc<<<256,blk,0,stream>>>(ep);

  k_mu_var_z<<<B,blk,0,stream>>>(hf,hb,Wmu,bmu,Wvar,bvar,noise,omu,ovar,oz,zws);
  k_zpart<<<B*G3/256,blk,0,stream>>>(zws,c1_Wih,c1_bih,zpart);
  k_h1init<<<B*H/256,blk,0,stream>>>(zws,Winit,binit,h1f,h1b0,idxb);

  DecP dp;
  dp.h1b0=h1b0; dp.h1b1=h1b1; dp.h2b0=h2b0; dp.h2b1=h2b1;
  dp.w1hh=wc1hh_b; dp.w2ih=wc2ih_b; dp.w2hh=wc2hh_b; dp.wout=wout_b;
  dp.bhh1=c1_bhh; dp.bih2=c2_bih; dp.bhh2=c2_bhh; dp.bout=bout;
  dp.zpart=zpart; dp.WT=WT; dp.h1f=h1f;
  dp.logits=logits; dp.lsbuf=lsbuf; dp.recon=orecon;
  dp.idxb=idxb; dp.bar=barD;
  k_dec<<<256,blk,0,stream>>>(dp);
}

// Round 5
// 9678.387 us; speedup vs baseline: 1.3900x; 1.3900x over previous
//
#include <hip/hip_runtime.h>
#include <cstdint>
#include <cstddef>

typedef __attribute__((ext_vector_type(8))) short bf16x8;
typedef __attribute__((ext_vector_type(4))) float f32x4;
#define DEVI __device__ __forceinline__

constexpr int B = 256, S = 128, V = 128, C = 16, H = 1024, Z = 256, NSTEP = 128;
constexpr int VC = V * C, G3 = 3 * H;
constexpr size_t BVC = (size_t)B * VC;

typedef __attribute__((address_space(1))) const unsigned short* gas_p;
typedef __attribute__((address_space(3))) unsigned short* las_p;

DEVI unsigned short f2bf(float f){unsigned u=__float_as_uint(f);u+=0x7fffu+((u>>16)&1u);return (unsigned short)(u>>16);}
DEVI float sigm(float x){return 1.f/(1.f+expf(-x));}
DEVI f32x4 MFMA(bf16x8 a,bf16x8 b,f32x4 c){return __builtin_amdgcn_mfma_f32_16x16x32_bf16(a,b,c,0,0,0);}
DEVI void stage16(const unsigned short* g, unsigned short* l){__builtin_amdgcn_global_load_lds((gas_p)g,(las_p)l,16,0,0);}

// ---- coherent (cross-XCD safe) access helpers ----
DEVI unsigned long long ldc8(const void* p){return __hip_atomic_load((const unsigned long long*)p,__ATOMIC_RELAXED,__HIP_MEMORY_SCOPE_AGENT);}
DEVI void stc8(void* p, unsigned long long v){__hip_atomic_store((unsigned long long*)p,v,__ATOMIC_RELAXED,__HIP_MEMORY_SCOPE_AGENT);}
DEVI unsigned ldc4(const void* p){return __hip_atomic_load((const unsigned*)p,__ATOMIC_RELAXED,__HIP_MEMORY_SCOPE_AGENT);}
DEVI void stc4(void* p, unsigned v){__hip_atomic_store((unsigned*)p,v,__ATOMIC_RELAXED,__HIP_MEMORY_SCOPE_AGENT);}
DEVI bf16x8 ldfragc(const unsigned short* p){
  union{bf16x8 v;unsigned long long q[2];}u;
  u.q[0]=ldc8(p); u.q[1]=ldc8(p+4); return u.v;
}
DEVI unsigned long long pack4(float a,float b,float c,float d){
  return (unsigned long long)f2bf(a)|((unsigned long long)f2bf(b)<<16)|((unsigned long long)f2bf(c)<<32)|((unsigned long long)f2bf(d)<<48);
}
DEVI unsigned long long packf2(float a,float b){
  return (unsigned long long)__float_as_uint(a)|((unsigned long long)__float_as_uint(b)<<32);
}

// ---- counted waits ----
DEVI void wv(int n){
  if(n==0)      asm volatile("s_waitcnt vmcnt(0)":::"memory");
  else if(n==4) asm volatile("s_waitcnt vmcnt(4)":::"memory");
  else if(n==8) asm volatile("s_waitcnt vmcnt(8)":::"memory");
  else if(n==10)asm volatile("s_waitcnt vmcnt(10)":::"memory");
  else if(n==12)asm volatile("s_waitcnt vmcnt(12)":::"memory");
  else if(n==16)asm volatile("s_waitcnt vmcnt(16)":::"memory");
  else if(n==20)asm volatile("s_waitcnt vmcnt(20)":::"memory");
}
DEVI void lg0(){asm volatile("s_waitcnt lgkmcnt(0)":::"memory");}
DEVI void cmb(){asm volatile("" ::: "memory");}
DEVI void drain_sync(){asm volatile("s_waitcnt vmcnt(0) lgkmcnt(0)":::"memory");__syncthreads();}

// ---- per-producer flag sync (64B-padded, no RMW, wave-parallel poll) ----
DEVI void waitflags(const unsigned* f,int base,int n,unsigned tgt){
  int lane=threadIdx.x&63;
  if (lane<n){
    const unsigned* a=&f[(size_t)(base+lane)<<4];
    while (ldc4(a)<tgt) __builtin_amdgcn_s_sleep(2);
  }
}
// poll on seq in high 16 bits; returns final flag value (valid in lanes<n)
DEVI unsigned waitseq(const unsigned* f,int base,int n,unsigned tgt){
  int lane=threadIdx.x&63; unsigned v=tgt<<16;
  if (lane<n){
    const unsigned* a=&f[(size_t)(base+lane)<<4];
    v=ldc4(a);
    while ((v>>16)<tgt){__builtin_amdgcn_s_sleep(2); v=ldc4(a);}
  }
  return v;
}

#define LDHD(SRC,KT,Ha,Hb) { (Ha)=ldfragc((SRC)+(size_t)mrow*H+((KT)<<6)+(l4<<3)); (Hb)=ldfragc((SRC)+(size_t)mrow*H+((KT)<<6)+((4+l4)<<3)); cmb(); }

// ---------------- prep kernels ----------------
__global__ void k_cvt(const float* __restrict__ src, unsigned short* __restrict__ dst, int n){
  for (int i=blockIdx.x*256+threadIdx.x;i<n;i+=gridDim.x*256) dst[i]=f2bf(src[i]);
}

__global__ void k_xt(const float* __restrict__ x, unsigned short* __restrict__ xtb){
  __shared__ float tile[32][33];
  int sb=blockIdx.x*32, rb=blockIdx.y*32, tx=threadIdx.x, ty=threadIdx.y;
  for (int i=ty;i<32;i+=8) tile[i][tx]=x[(size_t)(rb+i)*S+sb+tx];
  __syncthreads();
  for (int i=ty;i<32;i+=8) xtb[(size_t)(sb+i)*(B*V)+rb+tx]=f2bf(tile[tx][i]);
}

__global__ void k_wt(const float* __restrict__ w, float* __restrict__ wt){
  __shared__ float tile[32][33];
  int vb=blockIdx.x*32, nb=blockIdx.y*32, tx=threadIdx.x, ty=threadIdx.y;
  for (int i=ty;i<32;i+=8) tile[i][tx]=w[(size_t)(nb+i)*(VC+Z)+vb+tx];
  __syncthreads();
  for (int i=ty;i<32;i+=8) wt[(size_t)(vb+i)*G3+nb+tx]=tile[tx][i];
}

__global__ __launch_bounds__(256) void k_mu_var_z(const float* __restrict__ hf,const float* __restrict__ hb,
    const float* __restrict__ Wmu,const float* __restrict__ bmu,
    const float* __restrict__ Wvar,const float* __restrict__ bvar,
    const float* __restrict__ noise,
    float* __restrict__ omu,float* __restrict__ ovar,float* __restrict__ oz,float* __restrict__ zws){
  __shared__ float e[2*H];
  int b=blockIdx.x, t=threadIdx.x;
  for (int i=0;i<2*H/256;++i){int k=t+i*256; e[k]=(k<H)?hf[b*H+k]:hb[b*H+k-H];}
  __syncthreads();
  const float* wm=Wmu+(size_t)t*2*H; const float* wv2=Wvar+(size_t)t*2*H;
  float am=bmu[t], av=bvar[t];
  for (int k=0;k<2*H;++k){am+=e[k]*wm[k];av+=e[k]*wv2[k];}
  float vv=expf(av), zz=am+vv*noise[b*Z+t];
  omu[b*Z+t]=am; ovar[b*Z+t]=vv; oz[b*Z+t]=zz; zws[b*Z+t]=zz;
}

__global__ void k_zpart(const float* __restrict__ z,const float* __restrict__ c1Wih,
                        const float* __restrict__ bih,float* __restrict__ zpart){
  int idx=blockIdx.x*256+threadIdx.x;
  int b=idx/G3, n=idx%G3;
  const float* w=c1Wih+(size_t)n*(VC+Z)+VC;
  const float* zr=z+b*Z;
  float a=bih[n];
  for (int k=0;k<Z;++k) a+=zr[k]*w[k];
  zpart[idx]=a;
}

__global__ void k_h1init(const float* __restrict__ z,const float* __restrict__ Winit,
                         const float* __restrict__ binit,
                         float* __restrict__ h1f,unsigned short* __restrict__ h1b,unsigned* __restrict__ F4){
  int idx=blockIdx.x*256+threadIdx.x;
  int b=idx>>10, jj=idx&(H-1);
  const float* w=Winit+(size_t)jj*Z;
  const float* zr=z+b*Z;
  float a=binit[jj];
  for (int k=0;k<Z;++k) a+=zr[k]*w[k];
  float t=tanhf(a);
  h1f[idx]=t; h1b[idx]=f2bf(t);
  if (idx<B) F4[(size_t)idx<<4]=(unsigned)(VC-1);   // seq 0, idx VC-1
}

// ---------------- persistent encoder (256 blocks, 16 groups of 16) ----------------
struct EncP {
  const unsigned short *xtb,*wihf,*whhf,*wihb,*whhb;
  const float *bihf,*bhhf,*bihb,*bhhb;
  unsigned short *hf0,*hf1,*hb0,*hb1;
  float *hf,*hb;
  unsigned* FE;
};

#define ENC_MM(DB,H0,H1) { const unsigned short* bb=lw+(DB)*6144; \
  _Pragma("unroll") for (int kf=0;kf<2;++kf){ \
    const int sw=(((kf<<2)+l4)^(l15&7))<<3; \
    bf16x8 hh=kf?(H1):(H0); \
    _Pragma("unroll") for (int nj=0;nj<2;++nj){ \
      const int ro=((nj<<4)+l15)*64+sw; \
      bf16x8 w0=*(const bf16x8*)&bb[ro]; \
      bf16x8 w1=*(const bf16x8*)&bb[2048+ro]; \
      bf16x8 w2=*(const bf16x8*)&bb[4096+ro]; \
      aR[nj]=MFMA(w0,hh,aR[nj]); aZ[nj]=MFMA(w1,hh,aZ[nj]); aNH[nj]=MFMA(w2,hh,aNH[nj]); } } }

#define ENC_MMX(DB,XKT) { const unsigned short* bb=lw+(DB)*6144; \
  _Pragma("unroll") for (int kf=0;kf<2;++kf){ \
    const int ch=(kf<<2)+l4; const int sw=(ch^(l15&7))<<3; \
    bf16x8 hh=*(const bf16x8*)&P.xtb[(size_t)xs*(B*V)+(size_t)mrow*V+((XKT)<<6)+(ch<<3)]; \
    _Pragma("unroll") for (int nj=0;nj<2;++nj){ \
      const int ro=((nj<<4)+l15)*64+sw; \
      bf16x8 w0=*(const bf16x8*)&bb[ro]; \
      bf16x8 w1=*(const bf16x8*)&bb[2048+ro]; \
      bf16x8 w2=*(const bf16x8*)&bb[4096+ro]; \
      aR[nj]=MFMA(w0,hh,aR[nj]); aZ[nj]=MFMA(w1,hh,aZ[nj]); aNX[nj]=MFMA(w2,hh,aNX[nj]); } } }

__global__ __launch_bounds__(256,1) void k_enc(EncP P){
  __shared__ unsigned short lws[49152];
  const int tid=threadIdx.x, wave=tid>>6, lane=tid&63;
  const int l15=lane&15, l4=lane>>4, l8r=lane>>3, l8c=lane&7;
  const int bid=blockIdx.x, xcd=bid&7, q=bid>>3;
  const int dir=q>>4, q2=q&15, jt=(q2&1)*8+xcd, mt=q2>>1;
  const int wm=(wave&1)*16, wn=(wave>>1)*32;
  const int gbase=(bid>>4)<<4;       // 16-member group
  const unsigned short* wih=dir?P.wihb:P.wihf;
  const unsigned short* whh=dir?P.whhb:P.whhf;
  const float* bih=dir?P.bihb:P.bihf;
  const float* bhh=dir?P.bhhb:P.bhhf;
  unsigned short* hbuf[2]={dir?P.hb0:P.hf0, dir?P.hb1:P.hf1};
  unsigned short* lw=&lws[wave*12288];
  const int mrow=mt*32+wm+l15;

  f32x4 biR[2],biZ[2],biN[2],bhR[2],bhZ[2],bhN[2];
#pragma unroll
  for (int nj=0;nj<2;++nj){
    int j0=jt*64+wn+nj*16+(l4<<2);
    biR[nj]=*(const f32x4*)&bih[j0]; biZ[nj]=*(const f32x4*)&bih[H+j0]; biN[nj]=*(const f32x4*)&bih[2*H+j0];
    bhR[nj]=*(const f32x4*)&bhh[j0]; bhZ[nj]=*(const f32x4*)&bhh[H+j0]; bhN[nj]=*(const f32x4*)&bhh[2*H+j0];
  }
  float hreg[2][4]={};

  auto Wh=[&](int kt,int db){
    unsigned short* d=lw+db*6144;
#pragma unroll
    for (int g=0;g<3;++g)
#pragma unroll
      for (int i=0;i<4;++i)
        stage16(whh+(size_t)((g<<10)+jt*64+wn+i*8+l8r)*H+(kt<<6)+((l8c^l8r)<<3), d+(g*32+i*8)*64);
    cmb();
  };
  auto Wx=[&](int kt,int db){
    unsigned short* d=lw+db*6144;
#pragma unroll
    for (int g=0;g<3;++g)
#pragma unroll
      for (int i=0;i<4;++i)
        stage16(wih+(size_t)((g<<10)+jt*64+wn+i*8+l8r)*V+(kt<<6)+((l8c^l8r)<<3), d+(g*32+i*8)*64);
    cmb();
  };

  Wh(0,0); Wh(1,1);

  for (int s=0;s<S;++s){
    waitflags(P.FE,gbase,16,(unsigned)s);
    const unsigned short* hsrc=hbuf[s&1];
    unsigned short* hdst=hbuf[(s+1)&1];
    const int xs=dir?(S-1-s):s;
    bf16x8 hA0,hA1,hB0,hB1;
    f32x4 aR[2]={},aZ[2]={},aNH[2]={},aNX[2]={};
    LDHD(hsrc,0,hA0,hA1); LDHD(hsrc,1,hB0,hB1);
    wv(4);  ENC_MM(0,hA0,hA1); lg0(); Wh(2,0); LDHD(hsrc,2,hA0,hA1);
    for (int i=0;i<6;++i){
      wv(16); ENC_MM(1,hB0,hB1); lg0(); Wh(2*i+3,1); LDHD(hsrc,2*i+3,hB0,hB1);
      wv(16); ENC_MM(0,hA0,hA1); lg0(); Wh(2*i+4,0); LDHD(hsrc,2*i+4,hA0,hA1);
    }
    wv(16); ENC_MM(1,hB0,hB1); lg0(); Wh(15,1); LDHD(hsrc,15,hB0,hB1);
    wv(16); ENC_MM(0,hA0,hA1); lg0(); Wx(0,0);
    wv(12); ENC_MM(1,hB0,hB1); lg0(); Wx(1,1);
    wv(12); ENC_MMX(0,0); lg0();
    wv(0);  ENC_MMX(1,1); lg0();
#pragma unroll
    for (int nj=0;nj<2;++nj){
      int j0=jt*64+wn+nj*16+(l4<<2);
      float hv[4];
#pragma unroll
      for (int r=0;r<4;++r){
        float rg=sigm(aR[nj][r]+biR[nj][r]+bhR[nj][r]);
        float zg=sigm(aZ[nj][r]+biZ[nj][r]+bhZ[nj][r]);
        float nn=tanhf(aNX[nj][r]+biN[nj][r]+rg*(aNH[nj][r]+bhN[nj][r]));
        float hnew=(1.f-zg)*nn+zg*hreg[nj][r];
        hreg[nj][r]=hnew; hv[r]=hnew;
      }
      stc8(hdst+(size_t)mrow*H+j0, pack4(hv[0],hv[1],hv[2],hv[3]));
    }
    drain_sync();
    if (tid==0) stc4(&P.FE[(size_t)bid<<4],(unsigned)(s+1));
    Wh(0,0); Wh(1,1);               // prefetch next step before others catch up
  }
  float* hout=dir?P.hb:P.hf;
#pragma unroll
  for (int nj=0;nj<2;++nj){
    int j0=jt*64+wn+nj*16+(l4<<2);
    f32x4 v; v[0]=hreg[nj][0];v[1]=hreg[nj][1];v[2]=hreg[nj][2];v[3]=hreg[nj][3];
    *(f32x4*)&hout[(size_t)mrow*H+j0]=v;
  }
}

// ---------------- persistent decoder (256 blocks, 8 groups of 32) ----------------
struct DecP {
  unsigned short *h1b0,*h1b1,*h2b0,*h2b1;
  const unsigned short *w1hh,*w2ih,*w2hh,*wout;
  const float *bhh1,*bih2,*bhh2,*bout;
  const float *zpart,*WT,*h1f;
  float *logits,*lsbuf,*recon;
  unsigned *F1,*F2,*F3,*F4;
};

#define MM1(DB,H0,H1) { const unsigned short* bb=lw+(DB)*3072; \
  _Pragma("unroll") for (int kf=0;kf<2;++kf){ \
    const int sw=(((kf<<2)+l4)^(l15&7))<<3; const int ro=l15*64+sw; \
    bf16x8 w0=*(const bf16x8*)&bb[ro]; bf16x8 w1=*(const bf16x8*)&bb[1024+ro]; bf16x8 w2=*(const bf16x8*)&bb[2048+ro]; \
    bf16x8 hh=kf?(H1):(H0); \
    aR=MFMA(w0,hh,aR); aZ=MFMA(w1,hh,aZ); aN=MFMA(w2,hh,aN); } }

#define MM2(DB,A10,A11,A20,A21) { const unsigned short* bb=lw+(DB)*6144; \
  _Pragma("unroll") for (int kf=0;kf<2;++kf){ \
    const int sw=(((kf<<2)+l4)^(l15&7))<<3; const int ro=l15*64+sw; \
    bf16x8 wi0=*(const bf16x8*)&bb[ro];      bf16x8 wi1=*(const bf16x8*)&bb[1024+ro]; bf16x8 wi2=*(const bf16x8*)&bb[2048+ro]; \
    bf16x8 wh0=*(const bf16x8*)&bb[3072+ro]; bf16x8 wh1=*(const bf16x8*)&bb[4096+ro]; bf16x8 wh2=*(const bf16x8*)&bb[5120+ro]; \
    bf16x8 a1=kf?(A11):(A10), a2=kf?(A21):(A20); \
    aR=MFMA(wi0,a1,aR); aR=MFMA(wh0,a2,aR); \
    aZ=MFMA(wi1,a1,aZ); aZ=MFMA(wh1,a2,aZ); \
    aNI=MFMA(wi2,a1,aNI); aNH=MFMA(wh2,a2,aNH); } }

#define MM3(DB,H0,H1) { const unsigned short* bb=lw+(DB)*2048; \
  _Pragma("unroll") for (int kf=0;kf<2;++kf){ \
    const int sw=(((kf<<2)+l4)^(l15&7))<<3; \
    bf16x8 w0=*(const bf16x8*)&bb[l15*64+sw]; bf16x8 w1=*(const bf16x8*)&bb[(16+l15)*64+sw]; \
    bf16x8 hh=kf?(H1):(H0); \
    ac0=MFMA(w0,hh,ac0); ac1=MFMA(w1,hh,ac1); } }

__global__ __launch_bounds__(256,1) void k_dec(DecP P){
  __shared__ unsigned short lws[49152];
  __shared__ float sm_ls[VC];
  __shared__ float sm_rv[256];
  __shared__ int   sm_ri[256];
  const int tid=threadIdx.x, wave=tid>>6, lane=tid&63;
  const int l15=lane&15, l4=lane>>4, l8r=lane>>3, l8c=lane&7;
  const int bid=blockIdx.x, xcd=bid&7, q=bid>>3;
  const int jt=(q&3)*8+xcd, mt=q>>2;
  const int wm=(wave&1)*16, wn=(wave>>1)*16;
  const int wn3=(wave>>1)*32;
  const int base32=(bid>>5)<<5;     // 32-member group (same mt)
  unsigned short* lw=&lws[wave*12288];
  unsigned short* h1b[2]={P.h1b0,P.h1b1};
  unsigned short* h2b[2]={P.h2b0,P.h2b1};
  const int mrow=mt*32+wm+l15;
  const int j0=jt*32+wn+(l4<<2);

  f32x4 zR4=*(const f32x4*)&P.zpart[(size_t)mrow*G3+j0];
  f32x4 zZ4=*(const f32x4*)&P.zpart[(size_t)mrow*G3+H+j0];
  f32x4 zN4=*(const f32x4*)&P.zpart[(size_t)mrow*G3+2*H+j0];
  f32x4 b1R=*(const f32x4*)&P.bhh1[j0], b1Z=*(const f32x4*)&P.bhh1[H+j0], b1N=*(const f32x4*)&P.bhh1[2*H+j0];
  f32x4 c2Rv,c2Zv,biN2,bhN2;
  { f32x4 a=*(const f32x4*)&P.bih2[j0],   b2=*(const f32x4*)&P.bhh2[j0];   c2Rv=a+b2; }
  { f32x4 a=*(const f32x4*)&P.bih2[H+j0], b2=*(const f32x4*)&P.bhh2[H+j0]; c2Zv=a+b2; }
  biN2=*(const f32x4*)&P.bih2[2*H+j0]; bhN2=*(const f32x4*)&P.bhh2[2*H+j0];
  f32x4 bo0=*(const f32x4*)&P.bout[jt*64+wn3+(l4<<2)];
  f32x4 bo1=*(const f32x4*)&P.bout[jt*64+wn3+16+(l4<<2)];
  f32x4 h1i=*(const f32x4*)&P.h1f[(size_t)mrow*H+j0];
  float h1reg[4]={h1i[0],h1i[1],h1i[2],h1i[3]};
  float h2reg[4]={};

  auto W1i=[&](int kt,int db){
    unsigned short* d=lw+db*3072;
#pragma unroll
    for (int g=0;g<3;++g)
#pragma unroll
      for (int i=0;i<2;++i)
        stage16(P.w1hh+(size_t)((g<<10)+jt*32+wn+i*8+l8r)*H+(kt<<6)+((l8c^l8r)<<3), d+(g*16+i*8)*64);
    cmb();
  };
  auto W2i=[&](int kt,int db){
    unsigned short* d=lw+db*6144;
#pragma unroll
    for (int m=0;m<6;++m){
      const unsigned short* src=(m<3)?P.w2ih:P.w2hh;
      const int g=(m<3)?m:(m-3);
#pragma unroll
      for (int i=0;i<2;++i)
        stage16(src+(size_t)((g<<10)+jt*32+wn+i*8+l8r)*H+(kt<<6)+((l8c^l8r)<<3), d+(m*16+i*8)*64);
    }
    cmb();
  };
  auto W3i=[&](int kt,int db){
    unsigned short* d=lw+db*2048;
#pragma unroll
    for (int i=0;i<4;++i)
      stage16(P.wout+(size_t)(jt*64+wn3+i*8+l8r)*H+(kt<<6)+((l8c^l8r)<<3), d+i*8*64);
    cmb();
  };

  W1i(0,0); W1i(1,1);

  for (int t=0;t<NSTEP;++t){
    const int cur=t&1, nxt=cur^1;
    // ---------- stage1 ----------
    {
      unsigned fv=waitseq(P.F4,base32,32,(unsigned)t);
      int idxm=(int)(__shfl(fv,wm+l15)&0xffffu);
      const float* wtr=P.WT+(size_t)idxm*G3;
      f32x4 wR=*(const f32x4*)&wtr[j0], wZ=*(const f32x4*)&wtr[H+j0], wN=*(const f32x4*)&wtr[2*H+j0];
      const unsigned short* h1src=h1b[cur];
      bf16x8 hA0,hA1,hB0,hB1;
      f32x4 aR={},aZ={},aN={};
      LDHD(h1src,0,hA0,hA1); LDHD(h1src,1,hB0,hB1);
      wv(4);  MM1(0,hA0,hA1); lg0(); W1i(2,0); LDHD(h1src,2,hA0,hA1);
      for (int i=0;i<6;++i){
        wv(10); MM1(1,hB0,hB1); lg0(); W1i(2*i+3,1); LDHD(h1src,2*i+3,hB0,hB1);
        wv(10); MM1(0,hA0,hA1); lg0(); W1i(2*i+4,0); LDHD(h1src,2*i+4,hA0,hA1);
      }
      wv(10); MM1(1,hB0,hB1); lg0(); W1i(15,1); LDHD(h1src,15,hB0,hB1);
      wv(10); MM1(0,hA0,hA1); lg0();
      wv(0);  MM1(1,hB0,hB1); lg0();
      float hv[4];
#pragma unroll
      for (int r=0;r<4;++r){
        float rg=sigm(zR4[r]+wR[r]+aR[r]+b1R[r]);
        float zg=sigm(zZ4[r]+wZ[r]+aZ[r]+b1Z[r]);
        float nn=tanhf(zN4[r]+wN[r]+rg*(aN[r]+b1N[r]));
        float hnew=(1.f-zg)*nn+zg*h1reg[r];
        h1reg[r]=hnew; hv[r]=hnew;
      }
      stc8(h1b[nxt]+(size_t)mrow*H+j0, pack4(hv[0],hv[1],hv[2],hv[3]));
    }
    drain_sync();
    if (tid==0) stc4(&P.F1[(size_t)bid<<4],(unsigned)(t+1));
    W2i(0,0); W2i(1,1);
    waitflags(P.F1,base32,32,(unsigned)(t+1));
    // ---------- stage2 ----------
    {
      const unsigned short* s1=h1b[nxt];
      const unsigned short* s2=(t==0)?h1b[nxt]:h2b[cur];
      bf16x8 xA0,xA1,yA0,yA1,xB0,xB1,yB0,yB1;
      f32x4 aR={},aZ={},aNI={},aNH={};
      LDHD(s1,0,xA0,xA1); LDHD(s2,0,yA0,yA1); LDHD(s1,1,xB0,xB1); LDHD(s2,1,yB0,yB1);
      wv(8);  MM2(0,xA0,xA1,yA0,yA1); lg0(); W2i(2,0); LDHD(s1,2,xA0,xA1); LDHD(s2,2,yA0,yA1);
      for (int i=0;i<6;++i){
        wv(20); MM2(1,xB0,xB1,yB0,yB1); lg0(); W2i(2*i+3,1); LDHD(s1,2*i+3,xB0,xB1); LDHD(s2,2*i+3,yB0,yB1);
        wv(20); MM2(0,xA0,xA1,yA0,yA1); lg0(); W2i(2*i+4,0); LDHD(s1,2*i+4,xA0,xA1); LDHD(s2,2*i+4,yA0,yA1);
      }
      wv(20); MM2(1,xB0,xB1,yB0,yB1); lg0(); W2i(15,1); LDHD(s1,15,xB0,xB1); LDHD(s2,15,yB0,yB1);
      wv(20); MM2(0,xA0,xA1,yA0,yA1); lg0();
      wv(0);  MM2(1,xB0,xB1,yB0,yB1); lg0();
      float hv[4];
#pragma unroll
      for (int r=0;r<4;++r){
        float rg=sigm(aR[r]+c2Rv[r]);
        float zg=sigm(aZ[r]+c2Zv[r]);
        float nn=tanhf(aNI[r]+biN2[r]+rg*(aNH[r]+bhN2[r]));
        float hp=(t==0)?h1reg[r]:h2reg[r];
        float hnew=(1.f-zg)*nn+zg*hp;
        h2reg[r]=hnew; hv[r]=hnew;
      }
      stc8(h2b[nxt]+(size_t)mrow*H+j0, pack4(hv[0],hv[1],hv[2],hv[3]));
    }
    drain_sync();
    if (tid==0) stc4(&P.F2[(size_t)bid<<4],(unsigned)(t+1));
    W3i(0,0); W3i(1,1);
    waitflags(P.F2,base32,32,(unsigned)(t+1));
    // ---------- stage3 ----------
    {
      const unsigned short* hs=h2b[nxt];
      bf16x8 hA0,hA1,hB0,hB1;
      f32x4 ac0={},ac1={};
      LDHD(hs,0,hA0,hA1); LDHD(hs,1,hB0,hB1);
      wv(4); MM3(0,hA0,hA1); lg0(); W3i(2,0); LDHD(hs,2,hA0,hA1);
      for (int i=0;i<6;++i){
        wv(8); MM3(1,hB0,hB1); lg0(); W3i(2*i+3,1); LDHD(hs,2*i+3,hB0,hB1);
        wv(8); MM3(0,hA0,hA1); lg0(); W3i(2*i+4,0); LDHD(hs,2*i+4,hA0,hA1);
      }
      wv(8); MM3(1,hB0,hB1); lg0(); W3i(15,1); LDHD(hs,15,hB0,hB1);
      wv(8); MM3(0,hA0,hA1); lg0();
      wv(0); MM3(1,hB0,hB1); lg0();
      int n0=jt*64+wn3+(l4<<2);
      stc8(&P.logits[(size_t)mrow*VC+n0],    packf2(ac0[0]+bo0[0],ac0[1]+bo0[1]));
      stc8(&P.logits[(size_t)mrow*VC+n0+2],  packf2(ac0[2]+bo0[2],ac0[3]+bo0[3]));
      stc8(&P.logits[(size_t)mrow*VC+n0+16], packf2(ac1[0]+bo1[0],ac1[1]+bo1[1]));
      stc8(&P.logits[(size_t)mrow*VC+n0+18], packf2(ac1[2]+bo1[2],ac1[3]+bo1[3]));
    }
    drain_sync();
    if (tid==0) stc4(&P.F3[(size_t)bid<<4],(unsigned)(t+1));
    waitflags(P.F3,base32,32,(unsigned)(t+1));
    // ---------- stage4: log-softmax + argmax (row = bid) ----------
    int ri0;
    {
      const int b=bid;
#pragma unroll
      for (int i=0;i<4;++i){
        unsigned long long qq=ldc8(&P.logits[(size_t)b*VC+tid*8+i*2]);
        sm_ls[tid*8+i*2]  =__uint_as_float((unsigned)qq);
        sm_ls[tid*8+i*2+1]=__uint_as_float((unsigned)(qq>>32));
      }
      __syncthreads();
      if (tid<V){
        float mx=-1e30f;
        for (int c=0;c<C;++c) mx=fmaxf(mx,sm_ls[c*V+tid]);
        float sum=0.f;
        for (int c=0;c<C;++c) sum+=expf(sm_ls[c*V+tid]-mx);
        float lse=mx+logf(sum);
        for (int c=0;c<C;++c) sm_ls[c*V+tid]-=lse;
      }
      __syncthreads();
      float bv=-1e30f; int bi=0;
#pragma unroll
      for (int i=0;i<VC/256;++i){
        int n=i*256+tid; float v=sm_ls[n];
        if (v>bv){bv=v;bi=n;}
      }
      sm_rv[tid]=bv; sm_ri[tid]=bi;
      __syncthreads();
      for (int s2=128;s2>0;s2>>=1){
        if (tid<s2){
          float v2=sm_rv[tid+s2]; int i2=sm_ri[tid+s2];
          if (v2>sm_rv[tid]||(v2==sm_rv[tid]&&i2<sm_ri[tid])){sm_rv[tid]=v2;sm_ri[tid]=i2;}
        }
        __syncthreads();
      }
      ri0=sm_ri[0];
      float* dst=P.lsbuf+(size_t)(t&15)*BVC+(size_t)bid*VC;
#pragma unroll
      for (int i=0;i<4;++i)
        stc8(&dst[tid*8+i*2], packf2(sm_ls[tid*8+i*2],sm_ls[tid*8+i*2+1]));
    }
    drain_sync();
    if (tid==0) stc4(&P.F4[(size_t)bid<<4], ((unsigned)(t+1)<<16)|(unsigned)ri0);
    W1i(0,0); W1i(1,1);
    // ---------- flush (block-local) ----------
    if ((t&15)==15){
      const int t0=t-15;
      const size_t e0=((size_t)bid*256+tid)*8;
#pragma unroll
      for (int pe=0;pe<4;++pe){
        float va[16],vb[16];
#pragma unroll
        for (int j2=0;j2<16;++j2){
          unsigned long long qq=ldc8(&P.lsbuf[(size_t)j2*BVC+e0+pe*2]);
          va[j2]=__uint_as_float((unsigned)qq); vb[j2]=__uint_as_float((unsigned)(qq>>32));
        }
        float* d0=&P.recon[(e0+pe*2)*NSTEP+t0];
        float* d1=&P.recon[(e0+pe*2+1)*NSTEP+t0];
#pragma unroll
        for (int k=0;k<16;++k){ d0[k]=va[k]; d1[k]=vb[k]; }
      }
    }
  }
}

// ---------------- host orchestration ----------------
extern "C" void kernel_launch(void* const* d_in, const int* in_sizes, int n_in,
                              void* d_out, int out_size, void* d_ws, size_t ws_size,
                              hipStream_t stream) {
  const float* x        = (const float*)d_in[0];
  const float* noise    = (const float*)d_in[1];
  const float* gruf_Wih = (const float*)d_in[2];
  const float* gruf_Whh = (const float*)d_in[3];
  const float* gruf_bih = (const float*)d_in[4];
  const float* gruf_bhh = (const float*)d_in[5];
  const float* grub_Wih = (const float*)d_in[6];
  const float* grub_Whh = (const float*)d_in[7];
  const float* grub_bih = (const float*)d_in[8];
  const float* grub_bhh = (const float*)d_in[9];
  const float* Wmu      = (const float*)d_in[10];
  const float* bmu      = (const float*)d_in[11];
  const float* Wvar     = (const float*)d_in[12];
  const float* bvar     = (const float*)d_in[13];
  const float* Winit    = (const float*)d_in[14];
  const float* binit    = (const float*)d_in[15];
  const float* c1_Wih   = (const float*)d_in[16];
  const float* c1_Whh   = (const float*)d_in[17];
  const float* c1_bih   = (const float*)d_in[18];
  const float* c1_bhh   = (const float*)d_in[19];
  const float* c2_Wih   = (const float*)d_in[20];
  const float* c2_Whh   = (const float*)d_in[21];
  const float* c2_bih   = (const float*)d_in[22];
  const float* c2_bhh   = (const float*)d_in[23];
  const float* Wout     = (const float*)d_in[24];
  const float* bout     = (const float*)d_in[25];

  float* omu = (float*)d_out;
  float* ovar = omu + B*Z;
  float* oz = ovar + B*Z;
  float* orecon = oz + B*Z;

  char* p = (char*)d_ws;
  auto carve = [&](size_t bytes){ char* r = p; p += (bytes+255)&~(size_t)255; return r; };
  unsigned short* wihf_b  = (unsigned short*)carve((size_t)G3*V*2);
  unsigned short* whhf_b  = (unsigned short*)carve((size_t)G3*H*2);
  unsigned short* wihb_b  = (unsigned short*)carve((size_t)G3*V*2);
  unsigned short* whhb_b  = (unsigned short*)carve((size_t)G3*H*2);
  unsigned short* wc1hh_b = (unsigned short*)carve((size_t)G3*H*2);
  unsigned short* wc2ih_b = (unsigned short*)carve((size_t)G3*H*2);
  unsigned short* wc2hh_b = (unsigned short*)carve((size_t)G3*H*2);
  unsigned short* wout_b  = (unsigned short*)carve((size_t)VC*H*2);
  unsigned short* xtb     = (unsigned short*)carve((size_t)S*B*V*2);
  unsigned short* hf0     = (unsigned short*)carve((size_t)B*H*2);
  unsigned short* hf1     = (unsigned short*)carve((size_t)B*H*2);
  unsigned short* hb0     = (unsigned short*)carve((size_t)B*H*2);
  unsigned short* hb1     = (unsigned short*)carve((size_t)B*H*2);
  unsigned short* h1b0    = (unsigned short*)carve((size_t)B*H*2);
  unsigned short* h1b1    = (unsigned short*)carve((size_t)B*H*2);
  unsigned short* h2b0    = (unsigned short*)carve((size_t)B*H*2);
  unsigned short* h2b1    = (unsigned short*)carve((size_t)B*H*2);
  float* WT     = (float*)carve((size_t)VC*G3*4);
  float* zpart  = (float*)carve((size_t)B*G3*4);
  float* hf     = (float*)carve((size_t)B*H*4);
  float* hb     = (float*)carve((size_t)B*H*4);
  float* h1f    = (float*)carve((size_t)B*H*4);
  float* zws    = (float*)carve((size_t)B*Z*4);
  float* logits = (float*)carve((size_t)B*VC*4);
  float* lsbuf  = (float*)carve((size_t)16*BVC*4);
  unsigned* FE  = (unsigned*)carve(16384);
  unsigned* F1  = (unsigned*)carve(16384);
  unsigned* F2  = (unsigned*)carve(16384);
  unsigned* F3  = (unsigned*)carve(16384);
  unsigned* F4  = (unsigned*)carve(16384);

  dim3 blk(256);
  auto cvt=[&](const float* s, unsigned short* d, int n){
    int nb=(n+255)/256; if (nb>2048) nb=2048;
    k_cvt<<<nb,blk,0,stream>>>(s,d,n);
  };
  cvt(gruf_Wih,wihf_b,G3*V);
  cvt(gruf_Whh,whhf_b,G3*H);
  cvt(grub_Wih,wihb_b,G3*V);
  cvt(grub_Whh,whhb_b,G3*H);
  cvt(c1_Whh,wc1hh_b,G3*H);
  cvt(c2_Wih,wc2ih_b,G3*H);
  cvt(c2_Whh,wc2hh_b,G3*H);
  cvt(Wout,wout_b,VC*H);
  k_xt<<<dim3(S/32,(B*V)/32),dim3(32,8),0,stream>>>(x,xtb);
  k_wt<<<dim3(VC/32,G3/32),dim3(32,8),0,stream>>>(c1_Wih,WT);
  hipMemsetAsync(hf0,0,(size_t)B*H*2,stream);
  hipMemsetAsync(hb0,0,(size_t)B*H*2,stream);
  hipMemsetAsync(FE,0,5*16384,stream);   // FE,F1..F4 contiguous

  EncP ep;
  ep.xtb=xtb; ep.wihf=wihf_b; ep.whhf=whhf_b; ep.wihb=wihb_b; ep.whhb=whhb_b;
  ep.bihf=gruf_bih; ep.bhhf=gruf_bhh; ep.bihb=grub_bih; ep.bhhb=grub_bhh;
  ep.hf0=hf0; ep.hf1=hf1; ep.hb0=hb0; ep.hb1=hb1;
  ep.hf=hf; ep.hb=hb; ep.FE=FE;
  k_enc<<<256,blk,0,stream>>>(ep);

  k_mu_var_z<<<B,blk,0,stream>>>(hf,hb,Wmu,bmu,Wvar,bvar,noise,omu,ovar,oz,zws);
  k_zpart<<<B*G3/256,blk,0,stream>>>(zws,c1_Wih,c1_bih,zpart);
  k_h1init<<<B*H/256,blk,0,stream>>>(zws,Winit,binit,h1f,h1b0,F4);

  DecP dp;
  dp.h1b0=h1b0; dp.h1b1=h1b1; dp.h2b0=h2b0; dp.h2b1=h2b1;
  dp.w1hh=wc1hh_b; dp.w2ih=wc2ih_b; dp.w2hh=wc2hh_b; dp.wout=wout_b;
  dp.bhh1=c1_bhh; dp.bih2=c2_bih; dp.bhh2=c2_bhh; dp.bout=bout;
  dp.zpart=zpart; dp.WT=WT; dp.h1f=h1f;
  dp.logits=logits; dp.lsbuf=lsbuf; dp.recon=orecon;
  dp.F1=F1; dp.F2=F2; dp.F3=F3; dp.F4=F4;
  k_dec<<<256,blk,0,stream>>>(dp);
}

// Round 6
// 9206.132 us; speedup vs baseline: 1.4613x; 1.0513x over previous
//
#include <hip/hip_runtime.h>
#include <cstdint>
#include <cstddef>

typedef __attribute__((ext_vector_type(8))) short bf16x8;
typedef __attribute__((ext_vector_type(4))) float f32x4;
#define DEVI __device__ __forceinline__

constexpr int B = 256, S = 128, V = 128, C = 16, H = 1024, Z = 256, NSTEP = 128;
constexpr int VC = V * C, G3 = 3 * H;
constexpr size_t BVC = (size_t)B * VC;

typedef __attribute__((address_space(1))) const unsigned short* gas_p;
typedef __attribute__((address_space(3))) unsigned short* las_p;

DEVI unsigned short f2bf(float f){unsigned u=__float_as_uint(f);u+=0x7fffu+((u>>16)&1u);return (unsigned short)(u>>16);}
DEVI float sigm(float x){return 1.f/(1.f+expf(-x));}
DEVI f32x4 MFMA(bf16x8 a,bf16x8 b,f32x4 c){return __builtin_amdgcn_mfma_f32_16x16x32_bf16(a,b,c,0,0,0);}
DEVI void stage16(const unsigned short* g, unsigned short* l){__builtin_amdgcn_global_load_lds((gas_p)g,(las_p)l,16,0,0);}

DEVI unsigned long long ldc8(const void* p){return __hip_atomic_load((const unsigned long long*)p,__ATOMIC_RELAXED,__HIP_MEMORY_SCOPE_AGENT);}
DEVI void stc8(void* p, unsigned long long v){__hip_atomic_store((unsigned long long*)p,v,__ATOMIC_RELAXED,__HIP_MEMORY_SCOPE_AGENT);}
DEVI unsigned ldc4(const void* p){return __hip_atomic_load((const unsigned*)p,__ATOMIC_RELAXED,__HIP_MEMORY_SCOPE_AGENT);}
DEVI void stc4(void* p, unsigned v){__hip_atomic_store((unsigned*)p,v,__ATOMIC_RELAXED,__HIP_MEMORY_SCOPE_AGENT);}
DEVI unsigned long long pack4(float a,float b,float c,float d){
  return (unsigned long long)f2bf(a)|((unsigned long long)f2bf(b)<<16)|((unsigned long long)f2bf(c)<<32)|((unsigned long long)f2bf(d)<<48);
}
DEVI unsigned long long packf2(float a,float b){
  return (unsigned long long)__float_as_uint(a)|((unsigned long long)__float_as_uint(b)<<32);
}

DEVI void wv(int n){
  if(n==0)      asm volatile("s_waitcnt vmcnt(0)":::"memory");
  else if(n==2) asm volatile("s_waitcnt vmcnt(2)":::"memory");
  else if(n==3) asm volatile("s_waitcnt vmcnt(3)":::"memory");
  else if(n==4) asm volatile("s_waitcnt vmcnt(4)":::"memory");
  else if(n==6) asm volatile("s_waitcnt vmcnt(6)":::"memory");
}
DEVI void lg0(){asm volatile("s_waitcnt lgkmcnt(0)":::"memory");}
DEVI void cmb(){asm volatile("" ::: "memory");}

// per-producer flags: 64B padded, no RMW
DEVI void waitflags(const unsigned* f,int base,int n,unsigned tgt){
  int lane=threadIdx.x&63;
  if (lane<n){
    const unsigned* a=&f[(size_t)(base+lane)<<4];
    while (ldc4(a)<tgt) __builtin_amdgcn_s_sleep(1);
  }
}
// seq in high 8 bits
DEVI unsigned waitseq(const unsigned* f,int base,int n,unsigned tgt){
  int lane=threadIdx.x&63; unsigned v=tgt<<24;
  if (lane<n){
    const unsigned* a=&f[(size_t)(base+lane)<<4];
    v=ldc4(a);
    while ((v>>24)<tgt){__builtin_amdgcn_s_sleep(1); v=ldc4(a);}
  }
  return v;
}

// ---------------- prep kernels ----------------
__global__ void k_cvt(const float* __restrict__ src, unsigned short* __restrict__ dst, int n){
  for (int i=blockIdx.x*256+threadIdx.x;i<n;i+=gridDim.x*256) dst[i]=f2bf(src[i]);
}

__global__ void k_xt(const float* __restrict__ x, unsigned short* __restrict__ xtb){
  __shared__ float tile[32][33];
  int sb=blockIdx.x*32, rb=blockIdx.y*32, tx=threadIdx.x, ty=threadIdx.y;
  for (int i=ty;i<32;i+=8) tile[i][tx]=x[(size_t)(rb+i)*S+sb+tx];
  __syncthreads();
  for (int i=ty;i<32;i+=8) xtb[(size_t)(sb+i)*(B*V)+rb+tx]=f2bf(tile[tx][i]);
}

__global__ void k_wt(const float* __restrict__ w, float* __restrict__ wt){
  __shared__ float tile[32][33];
  int vb=blockIdx.x*32, nb=blockIdx.y*32, tx=threadIdx.x, ty=threadIdx.y;
  for (int i=ty;i<32;i+=8) tile[i][tx]=w[(size_t)(nb+i)*(VC+Z)+vb+tx];
  __syncthreads();
  for (int i=ty;i<32;i+=8) wt[(size_t)(vb+i)*G3+nb+tx]=tile[tx][i];
}

__global__ __launch_bounds__(256) void k_mu_var_z(const float* __restrict__ hf,const float* __restrict__ hb,
    const float* __restrict__ Wmu,const float* __restrict__ bmu,
    const float* __restrict__ Wvar,const float* __restrict__ bvar,
    const float* __restrict__ noise,
    float* __restrict__ omu,float* __restrict__ ovar,float* __restrict__ oz,float* __restrict__ zws){
  __shared__ float e[2*H];
  int b=blockIdx.x, t=threadIdx.x;
  for (int i=0;i<2*H/256;++i){int k=t+i*256; e[k]=(k<H)?hf[b*H+k]:hb[b*H+k-H];}
  __syncthreads();
  const float* wm=Wmu+(size_t)t*2*H; const float* wv2=Wvar+(size_t)t*2*H;
  float am=bmu[t], av=bvar[t];
  for (int k=0;k<2*H;++k){am+=e[k]*wm[k];av+=e[k]*wv2[k];}
  float vv=expf(av), zz=am+vv*noise[b*Z+t];
  omu[b*Z+t]=am; ovar[b*Z+t]=vv; oz[b*Z+t]=zz; zws[b*Z+t]=zz;
}

__global__ void k_zpart(const float* __restrict__ z,const float* __restrict__ c1Wih,
                        const float* __restrict__ bih,float* __restrict__ zpart){
  int idx=blockIdx.x*256+threadIdx.x;
  int b=idx/G3, n=idx%G3;
  const float* w=c1Wih+(size_t)n*(VC+Z)+VC;
  const float* zr=z+b*Z;
  float a=bih[n];
  for (int k=0;k<Z;++k) a+=zr[k]*w[k];
  zpart[idx]=a;
}

__global__ void k_h1init(const float* __restrict__ z,const float* __restrict__ Winit,
                         const float* __restrict__ binit,
                         float* __restrict__ h1f,unsigned short* __restrict__ h1b,unsigned* __restrict__ F4){
  int idx=blockIdx.x*256+threadIdx.x;
  int b=idx>>10, jj=idx&(H-1);
  const float* w=Winit+(size_t)jj*Z;
  const float* zr=z+b*Z;
  float a=binit[jj];
  for (int k=0;k<Z;++k) a+=zr[k]*w[k];
  float t=tanhf(a);
  h1f[idx]=t; h1b[idx]=f2bf(t);
  if (idx<128) F4[(size_t)idx<<4]=((unsigned)(VC-1)<<12)|(unsigned)(VC-1); // seq 0
}

// ---------------- persistent encoder: 256 blocks x 512 thr ----------------
// bid = dir*128 + mt*8 + jt ; mt in 0..15 (16 rows), jt in 0..7 (128 H-cols)
// LDS: panel h [16][1024] @0 (16384 ush) | x [16][128] @16384 (2048) | weights @18432 (8 waves * 3 bufs * 3 tiles * 512)
struct EncP {
  const unsigned short *xtb,*wihf,*whhf,*wihb,*whhb;
  const float *bihf,*bhhf,*bihb,*bhhb;
  unsigned short *hf0,*hf1,*hb0,*hb1;
  float *hf,*hb;
  unsigned* FE;
};

__global__ __launch_bounds__(512,1) void k_enc(EncP P){
  __shared__ unsigned short L[55296];
  const int tid=threadIdx.x, wave=tid>>6, lane=tid&63;
  const int l15=lane&15, l4=lane>>4;
  const int r8=lane>>2, pcl=lane&3;
  const int csw=(pcl-(r8>>1))&3;
  const int bid=blockIdx.x, jt=bid&7, mt=(bid>>3)&15, dir=bid>>7;
  const int g8=bid&~7;
  const unsigned short* wih=dir?P.wihb:P.wihf;
  const unsigned short* whh=dir?P.whhb:P.whhf;
  const float* bih=dir?P.bihb:P.bihf;
  const float* bhh=dir?P.bhhb:P.bhhf;
  unsigned short* hbuf[2]={dir?P.hb0:P.hf0, dir?P.hb1:P.hf1};
  const int m=mt*16+l15;
  const int j0=jt*128+wave*16+(l4<<2);
  const int WBe=18432;

  f32x4 cR,cZ,bNi,bNh;
  { f32x4 a=*(const f32x4*)&bih[j0],   b2=*(const f32x4*)&bhh[j0];   cR=a+b2; }
  { f32x4 a=*(const f32x4*)&bih[H+j0], b2=*(const f32x4*)&bhh[H+j0]; cZ=a+b2; }
  bNi=*(const f32x4*)&bih[2*H+j0]; bNh=*(const f32x4*)&bhh[2*H+j0];
  float hreg[4]={};

  auto W=[&](int kt,int buf){
    unsigned short* d=&L[WBe + wave*4608 + buf*1536];
    if (kt<32){
#pragma unroll
      for (int g=0;g<3;++g)
        stage16(whh + (size_t)((g<<10)+jt*128+wave*16+r8)*H + (kt<<5) + csw*8, d+(g<<9));
    } else {
      int kx=kt-32;
#pragma unroll
      for (int g=0;g<3;++g)
        stage16(wih + (size_t)((g<<10)+jt*128+wave*16+r8)*V + (kx<<5) + csw*8, d+(g<<9));
    }
    cmb();
  };

  for (int s=0;s<S;++s){
    waitflags(P.FE,g8,8,(unsigned)s);
    // ---- panel load (h 32KB coherent + x 4KB cached) ----
    {
      const unsigned short* hs=hbuf[s&1] + (size_t)mt*16*H;
      unsigned long long q[8];
#pragma unroll
      for (int i=0;i<8;++i) q[i]=ldc8(hs + (i*512+tid)*4);
#pragma unroll
      for (int i=0;i<8;++i){
        int e=i*512+tid, row=e>>8, u=e&255, c=u>>1;
        int ph=(c&~7)|((c+(row>>1))&7);
        *(unsigned long long*)&L[row*1024 + ph*8 + (u&1)*4]=q[i];
      }
      const int xs=dir?(S-1-s):s;
      if (tid<256){
        int row=tid>>4, c=tid&15;
        uint4 v=*(const uint4*)&P.xtb[(size_t)xs*(B*V)+(size_t)(mt*16+row)*V+(c<<3)];
        int ph=(c&~7)|((c+(row>>1))&7);
        *(uint4*)&L[16384 + row*128 + ph*8]=v;
      }
    }
    __syncthreads();
    W(0,0); W(1,1); W(2,2);
    f32x4 aR={},aZ={},aNH={},aNX={};
    int buf=0;
    for (int kt=0;kt<36;++kt){
      if (kt<34) wv(6); else if (kt==34) wv(3); else wv(0);
      bf16x8 b;
      if (kt<32){
        int c=(kt<<2)+l4, ph=(c&~7)|((c+(l15>>1))&7);
        b=*(const bf16x8*)&L[l15*1024 + ph*8];
      } else {
        int c=((kt-32)<<2)+l4, ph=(c&~7)|((c+(l15>>1))&7);
        b=*(const bf16x8*)&L[16384 + l15*128 + ph*8];
      }
      int ab=WBe + wave*4608 + buf*1536 + l15*32 + (((l4+(l15>>1))&3)<<3);
      bf16x8 a0=*(const bf16x8*)&L[ab];
      bf16x8 a1=*(const bf16x8*)&L[ab+512];
      bf16x8 a2=*(const bf16x8*)&L[ab+1024];
      aR=MFMA(a0,b,aR); aZ=MFMA(a1,b,aZ);
      if (kt<32) aNH=MFMA(a2,b,aNH); else aNX=MFMA(a2,b,aNX);
      lg0();
      if (kt<33) W(kt+3,buf);
      buf=(buf==2)?0:buf+1;
    }
    float hv[4];
#pragma unroll
    for (int r=0;r<4;++r){
      float rg=sigm(aR[r]+cR[r]);
      float zg=sigm(aZ[r]+cZ[r]);
      float nn=tanhf(aNX[r]+bNi[r]+rg*(aNH[r]+bNh[r]));
      float hnew=(1.f-zg)*nn+zg*hreg[r];
      hreg[r]=hnew; hv[r]=hnew;
    }
    stc8(hbuf[(s+1)&1] + (size_t)m*H + j0, pack4(hv[0],hv[1],hv[2],hv[3]));
    wv(0); __syncthreads();
    if (tid==0) stc4(&P.FE[(size_t)bid<<4],(unsigned)(s+1));
  }
  float* hout=dir?P.hb:P.hf;
  f32x4 v; v[0]=hreg[0];v[1]=hreg[1];v[2]=hreg[2];v[3]=hreg[3];
  *(f32x4*)&hout[(size_t)m*H+j0]=v;
}

// ---------------- persistent decoder: 128 blocks x 512 thr ----------------
// bid = mt*8 + jb ; mt 0..15 (16 rows), jb 0..7 (128 gate-cols st1/2, 256 VC-cols st3, 2 rows st4)
// LDS ush: PA @0 (16384) | PB @16384 (16384) | W @32768 (36864) ; SM overlays @32768
struct DecP {
  unsigned short *h1b0,*h1b1,*h2b0,*h2b1;
  const unsigned short *w1hh,*w2ih,*w2hh,*wout;
  const float *bhh1,*bih2,*bhh2,*bout;
  const float *zpart,*WT,*h1f;
  float *logits,*lsbuf,*recon;
  unsigned *F1,*F2,*F3,*F4;
};

__global__ __launch_bounds__(512,1) void k_dec(DecP P){
  __shared__ unsigned short L[69632];
  const int tid=threadIdx.x, wave=tid>>6, lane=tid&63;
  const int l15=lane&15, l4=lane>>4;
  const int r8=lane>>2, pcl=lane&3;
  const int csw=(pcl-(r8>>1))&3;
  const int bid=blockIdx.x, jb=bid&7, mt=bid>>3;
  const int g8=bid&~7;
  const int WB=32768;
  unsigned short* h1b[2]={P.h1b0,P.h1b1};
  unsigned short* h2b[2]={P.h2b0,P.h2b1};
  const int m=mt*16+l15;
  const int j0=jb*128+wave*16+(l4<<2);
  const int n0=jb*256+wave*32+(l4<<2);

  f32x4 zR4=*(const f32x4*)&P.zpart[(size_t)m*G3+j0];
  f32x4 zZ4=*(const f32x4*)&P.zpart[(size_t)m*G3+H+j0];
  f32x4 zN4=*(const f32x4*)&P.zpart[(size_t)m*G3+2*H+j0];
  f32x4 b1R=*(const f32x4*)&P.bhh1[j0], b1Z=*(const f32x4*)&P.bhh1[H+j0], b1N=*(const f32x4*)&P.bhh1[2*H+j0];
  f32x4 c2R,c2Z,biN2,bhN2;
  { f32x4 a=*(const f32x4*)&P.bih2[j0],   b2=*(const f32x4*)&P.bhh2[j0];   c2R=a+b2; }
  { f32x4 a=*(const f32x4*)&P.bih2[H+j0], b2=*(const f32x4*)&P.bhh2[H+j0]; c2Z=a+b2; }
  biN2=*(const f32x4*)&P.bih2[2*H+j0]; bhN2=*(const f32x4*)&P.bhh2[2*H+j0];
  f32x4 bo0=*(const f32x4*)&P.bout[n0];
  f32x4 bo1=*(const f32x4*)&P.bout[n0+16];
  f32x4 h1i=*(const f32x4*)&P.h1f[(size_t)m*H+j0];
  float h1reg[4]={h1i[0],h1i[1],h1i[2],h1i[3]};
  float h2reg[4]={};

  auto loadPanel=[&](const unsigned short* src,int base){
    const unsigned short* hs=src + (size_t)mt*16*H;
    unsigned long long q[8];
#pragma unroll
    for (int i=0;i<8;++i) q[i]=ldc8(hs + (i*512+tid)*4);
#pragma unroll
    for (int i=0;i<8;++i){
      int e=i*512+tid, row=e>>8, u=e&255, c=u>>1;
      int ph=(c&~7)|((c+(row>>1))&7);
      *(unsigned long long*)&L[base + row*1024 + ph*8 + (u&1)*4]=q[i];
    }
  };
  auto PFRAG=[&](int base,int kt)->bf16x8{
    int c=(kt<<2)+l4, ph=(c&~7)|((c+(l15>>1))&7);
    return *(const bf16x8*)&L[base + l15*1024 + ph*8];
  };
  auto W1=[&](int kt,int buf){
    unsigned short* d=&L[WB + wave*4608 + buf*1536];
#pragma unroll
    for (int g=0;g<3;++g)
      stage16(P.w1hh + (size_t)((g<<10)+jb*128+wave*16+r8)*H + (kt<<5) + csw*8, d+(g<<9));
    cmb();
  };
  auto W2=[&](int kt,int buf){
    unsigned short* d=&L[WB + wave*4608 + buf*1536];
    const unsigned short* src=(kt<32)?P.w2ih:P.w2hh;
    int ko=(kt<32)?(kt<<5):((kt-32)<<5);
#pragma unroll
    for (int g=0;g<3;++g)
      stage16(src + (size_t)((g<<10)+jb*128+wave*16+r8)*H + ko + csw*8, d+(g<<9));
    cmb();
  };
  auto W3=[&](int kt,int buf){
    unsigned short* d=&L[WB + wave*3072 + buf*1024];
#pragma unroll
    for (int nt=0;nt<2;++nt)
      stage16(P.wout + (size_t)(jb*256+wave*32+(nt<<4)+r8)*H + (kt<<5) + csw*8, d+(nt<<9));
    cmb();
  };

  loadPanel(h1b[0],0);   // t=0 stage1 panel

  for (int t=0;t<NSTEP;++t){
    const int cur=t&1, nxt=cur^1;
    // ========== stage1 ==========
    {
      unsigned fv=waitseq(P.F4,g8,8,(unsigned)t);
      unsigned vv=__shfl(fv,(l15>>1));
      int idxm=(int)((vv>>(12*(l15&1)))&0xfffu);
      const float* wtr=P.WT+(size_t)idxm*G3;
      f32x4 wR=*(const f32x4*)&wtr[j0];
      f32x4 wZ=*(const f32x4*)&wtr[H+j0];
      f32x4 wN=*(const f32x4*)&wtr[2*H+j0];
      __syncthreads();
      W1(0,0); W1(1,1); W1(2,2);
      f32x4 aR={},aZ={},aN={};
      int buf=0;
      for (int kt=0;kt<32;++kt){
        if (kt<30) wv(6); else if (kt==30) wv(3); else wv(0);
        bf16x8 b=PFRAG(0,kt);
        int ab=WB + wave*4608 + buf*1536 + l15*32 + (((l4+(l15>>1))&3)<<3);
        bf16x8 a0=*(const bf16x8*)&L[ab];
        bf16x8 a1=*(const bf16x8*)&L[ab+512];
        bf16x8 a2=*(const bf16x8*)&L[ab+1024];
        aR=MFMA(a0,b,aR); aZ=MFMA(a1,b,aZ); aN=MFMA(a2,b,aN);
        lg0();
        if (kt<29) W1(kt+3,buf);
        buf=(buf==2)?0:buf+1;
      }
      float hv[4];
#pragma unroll
      for (int r=0;r<4;++r){
        float rg=sigm(zR4[r]+wR[r]+aR[r]+b1R[r]);
        float zg=sigm(zZ4[r]+wZ[r]+aZ[r]+b1Z[r]);
        float nn=tanhf(zN4[r]+wN[r]+rg*(aN[r]+b1N[r]));
        float hnew=(1.f-zg)*nn+zg*h1reg[r];
        h1reg[r]=hnew; hv[r]=hnew;
      }
      stc8(h1b[nxt]+(size_t)m*H+j0, pack4(hv[0],hv[1],hv[2],hv[3]));
      wv(0); __syncthreads();
      if (tid==0) stc4(&P.F1[(size_t)bid<<4],(unsigned)(t+1));
    }
    // ========== stage2 ==========
    {
      waitflags(P.F1,g8,8,(unsigned)(t+1));
      loadPanel(h1b[nxt],0);
      loadPanel((t==0)?h1b[nxt]:h2b[cur],16384);
      __syncthreads();
      W2(0,0); W2(1,1); W2(2,2);
      f32x4 aR={},aZ={},aNI={},aNH={};
      int buf=0;
      for (int kt=0;kt<64;++kt){
        if (kt<62) wv(6); else if (kt==62) wv(3); else wv(0);
        bf16x8 b=(kt<32)?PFRAG(0,kt):PFRAG(16384,kt-32);
        int ab=WB + wave*4608 + buf*1536 + l15*32 + (((l4+(l15>>1))&3)<<3);
        bf16x8 a0=*(const bf16x8*)&L[ab];
        bf16x8 a1=*(const bf16x8*)&L[ab+512];
        bf16x8 a2=*(const bf16x8*)&L[ab+1024];
        aR=MFMA(a0,b,aR); aZ=MFMA(a1,b,aZ);
        if (kt<32) aNI=MFMA(a2,b,aNI); else aNH=MFMA(a2,b,aNH);
        lg0();
        if (kt<61) W2(kt+3,buf);
        buf=(buf==2)?0:buf+1;
      }
      float hv[4];
#pragma unroll
      for (int r=0;r<4;++r){
        float rg=sigm(aR[r]+c2R[r]);
        float zg=sigm(aZ[r]+c2Z[r]);
        float nn=tanhf(aNI[r]+biN2[r]+rg*(aNH[r]+bhN2[r]));
        float hp=(t==0)?h1reg[r]:h2reg[r];
        float hnew=(1.f-zg)*nn+zg*hp;
        h2reg[r]=hnew; hv[r]=hnew;
      }
      stc8(h2b[nxt]+(size_t)m*H+j0, pack4(hv[0],hv[1],hv[2],hv[3]));
      wv(0); __syncthreads();
      if (tid==0) stc4(&P.F2[(size_t)bid<<4],(unsigned)(t+1));
    }
    // ========== stage3 ==========
    {
      waitflags(P.F2,g8,8,(unsigned)(t+1));
      loadPanel(h2b[nxt],0);
      __syncthreads();
      W3(0,0); W3(1,1); W3(2,2);
      f32x4 ac0={},ac1={};
      int buf=0;
      for (int kt=0;kt<32;++kt){
        if (kt<30) wv(4); else if (kt==30) wv(2); else wv(0);
        bf16x8 b=PFRAG(0,kt);
        int ab=WB + wave*3072 + buf*1024 + l15*32 + (((l4+(l15>>1))&3)<<3);
        bf16x8 a0=*(const bf16x8*)&L[ab];
        bf16x8 a1=*(const bf16x8*)&L[ab+512];
        ac0=MFMA(a0,b,ac0); ac1=MFMA(a1,b,ac1);
        lg0();
        if (kt<29) W3(kt+3,buf);
        buf=(buf==2)?0:buf+1;
      }
      stc8(&P.logits[(size_t)m*VC+n0],    packf2(ac0[0]+bo0[0],ac0[1]+bo0[1]));
      stc8(&P.logits[(size_t)m*VC+n0+2],  packf2(ac0[2]+bo0[2],ac0[3]+bo0[3]));
      stc8(&P.logits[(size_t)m*VC+n0+16], packf2(ac1[0]+bo1[0],ac1[1]+bo1[1]));
      stc8(&P.logits[(size_t)m*VC+n0+18], packf2(ac1[2]+bo1[2],ac1[3]+bo1[3]));
      wv(0); __syncthreads();
      if (tid==0) stc4(&P.F3[(size_t)bid<<4],(unsigned)(t+1));
    }
    // ========== stage4: log-softmax + argmax (2 rows/block) ==========
    {
      waitflags(P.F3,g8,8,(unsigned)(t+1));
      float* SM=(float*)&L[WB];           // ls[2][2048] @0, rv[2][256] @4096, ri @4608
      const int row=tid>>8, t2=tid&255;
      const int b4=bid*2+row;
#pragma unroll
      for (int i=0;i<4;++i){
        unsigned long long q=ldc8(&P.logits[(size_t)b4*VC + t2*8 + i*2]);
        SM[row*2048+t2*8+i*2]  =__uint_as_float((unsigned)q);
        SM[row*2048+t2*8+i*2+1]=__uint_as_float((unsigned)(q>>32));
      }
      __syncthreads();
      if (t2<V){
        float mx=-1e30f;
        for (int c=0;c<C;++c) mx=fmaxf(mx,SM[row*2048+c*V+t2]);
        float su=0.f;
        for (int c=0;c<C;++c) su+=expf(SM[row*2048+c*V+t2]-mx);
        float lse=mx+logf(su);
        for (int c=0;c<C;++c) SM[row*2048+c*V+t2]-=lse;
      }
      __syncthreads();
      float bv=-1e30f; int bi=0;
#pragma unroll
      for (int i=0;i<8;++i){
        int n=t2*8+i; float v=SM[row*2048+n];
        if (v>bv){bv=v;bi=n;}
      }
      float* RV=SM+4096; int* RI=(int*)(SM+4608);
      RV[row*256+t2]=bv; RI[row*256+t2]=bi;
      __syncthreads();
      for (int s2=128;s2>0;s2>>=1){
        if (t2<s2){
          float v2=RV[row*256+t2+s2]; int i2=RI[row*256+t2+s2];
          if (v2>RV[row*256+t2]||(v2==RV[row*256+t2]&&i2<RI[row*256+t2])){RV[row*256+t2]=v2;RI[row*256+t2]=i2;}
        }
        __syncthreads();
      }
      float* dst=P.lsbuf+(size_t)(t&15)*BVC+(size_t)b4*VC;
#pragma unroll
      for (int i=0;i<4;++i)
        stc8(&dst[t2*8+i*2], packf2(SM[row*2048+t2*8+i*2],SM[row*2048+t2*8+i*2+1]));
      wv(0); __syncthreads();
      if (tid==0){
        unsigned i0=(unsigned)RI[0], i1=(unsigned)RI[256];
        stc4(&P.F4[(size_t)bid<<4], ((unsigned)(t+1)<<24)|(i1<<12)|i0);
      }
    }
    // ---------- flush 16 staged steps -> recon ----------
    if ((t&15)==15){
      const int t0=t-15;
      const size_t e0=(size_t)bid*4096 + (size_t)tid*8;
#pragma unroll
      for (int pp=0;pp<4;++pp){
        float va[16],vb[16];
#pragma unroll
        for (int j2=0;j2<16;++j2){
          unsigned long long q=ldc8(&P.lsbuf[(size_t)j2*BVC + e0 + pp*2]);
          va[j2]=__uint_as_float((unsigned)q); vb[j2]=__uint_as_float((unsigned)(q>>32));
        }
        float* d0=&P.recon[(e0+pp*2)*NSTEP+t0];
        float* d1=&P.recon[(e0+pp*2+1)*NSTEP+t0];
#pragma unroll
        for (int k=0;k<16;++k){ d0[k]=va[k]; d1[k]=vb[k]; }
      }
    }
    // ---------- preload next stage1 panel (hides LLC latency under F4 poll) ----------
    loadPanel(h1b[nxt],0);
  }
}

// ---------------- host orchestration ----------------
extern "C" void kernel_launch(void* const* d_in, const int* in_sizes, int n_in,
                              void* d_out, int out_size, void* d_ws, size_t ws_size,
                              hipStream_t stream) {
  const float* x        = (const float*)d_in[0];
  const float* noise    = (const float*)d_in[1];
  const float* gruf_Wih = (const float*)d_in[2];
  const float* gruf_Whh = (const float*)d_in[3];
  const float* gruf_bih = (const float*)d_in[4];
  const float* gruf_bhh = (const float*)d_in[5];
  const float* grub_Wih = (const float*)d_in[6];
  const float* grub_Whh = (const float*)d_in[7];
  const float* grub_bih = (const float*)d_in[8];
  const float* grub_bhh = (const float*)d_in[9];
  const float* Wmu      = (const float*)d_in[10];
  const float* bmu      = (const float*)d_in[11];
  const float* Wvar     = (const float*)d_in[12];
  const float* bvar     = (const float*)d_in[13];
  const float* Winit    = (const float*)d_in[14];
  const float* binit    = (const float*)d_in[15];
  const float* c1_Wih   = (const float*)d_in[16];
  const float* c1_Whh   = (const float*)d_in[17];
  const float* c1_bih   = (const float*)d_in[18];
  const float* c1_bhh   = (const float*)d_in[19];
  const float* c2_Wih   = (const float*)d_in[20];
  const float* c2_Whh   = (const float*)d_in[21];
  const float* c2_bih   = (const float*)d_in[22];
  const float* c2_bhh   = (const float*)d_in[23];
  const float* Wout     = (const float*)d_in[24];
  const float* bout     = (const float*)d_in[25];

  float* omu = (float*)d_out;
  float* ovar = omu + B*Z;
  float* oz = ovar + B*Z;
  float* orecon = oz + B*Z;

  char* p = (char*)d_ws;
  auto carve = [&](size_t bytes){ char* r = p; p += (bytes+255)&~(size_t)255; return r; };
  unsigned short* wihf_b  = (unsigned short*)carve((size_t)G3*V*2);
  unsigned short* whhf_b  = (unsigned short*)carve((size_t)G3*H*2);
  unsigned short* wihb_b  = (unsigned short*)carve((size_t)G3*V*2);
  unsigned short* whhb_b  = (unsigned short*)carve((size_t)G3*H*2);
  unsigned short* wc1hh_b = (unsigned short*)carve((size_t)G3*H*2);
  unsigned short* wc2ih_b = (unsigned short*)carve((size_t)G3*H*2);
  unsigned short* wc2hh_b = (unsigned short*)carve((size_t)G3*H*2);
  unsigned short* wout_b  = (unsigned short*)carve((size_t)VC*H*2);
  unsigned short* xtb     = (unsigned short*)carve((size_t)S*B*V*2);
  unsigned short* hf0     = (unsigned short*)carve((size_t)B*H*2);
  unsigned short* hf1     = (unsigned short*)carve((size_t)B*H*2);
  unsigned short* hb0     = (unsigned short*)carve((size_t)B*H*2);
  unsigned short* hb1     = (unsigned short*)carve((size_t)B*H*2);
  unsigned short* h1b0    = (unsigned short*)carve((size_t)B*H*2);
  unsigned short* h1b1    = (unsigned short*)carve((size_t)B*H*2);
  unsigned short* h2b0    = (unsigned short*)carve((size_t)B*H*2);
  unsigned short* h2b1    = (unsigned short*)carve((size_t)B*H*2);
  float* WT     = (float*)carve((size_t)VC*G3*4);
  float* zpart  = (float*)carve((size_t)B*G3*4);
  float* hf     = (float*)carve((size_t)B*H*4);
  float* hb     = (float*)carve((size_t)B*H*4);
  float* h1f    = (float*)carve((size_t)B*H*4);
  float* zws    = (float*)carve((size_t)B*Z*4);
  float* logits = (float*)carve((size_t)B*VC*4);
  float* lsbuf  = (float*)carve((size_t)16*BVC*4);
  unsigned* FE  = (unsigned*)carve(16384);
  unsigned* F1  = (unsigned*)carve(8192);
  unsigned* F2  = (unsigned*)carve(8192);
  unsigned* F3  = (unsigned*)carve(8192);
  unsigned* F4  = (unsigned*)carve(8192);

  dim3 b256(256);
  auto cvt=[&](const float* s, unsigned short* d, int n){
    int nb=(n+255)/256; if (nb>2048) nb=2048;
    k_cvt<<<nb,b256,0,stream>>>(s,d,n);
  };
  cvt(gruf_Wih,wihf_b,G3*V);
  cvt(gruf_Whh,whhf_b,G3*H);
  cvt(grub_Wih,wihb_b,G3*V);
  cvt(grub_Whh,whhb_b,G3*H);
  cvt(c1_Whh,wc1hh_b,G3*H);
  cvt(c2_Wih,wc2ih_b,G3*H);
  cvt(c2_Whh,wc2hh_b,G3*H);
  cvt(Wout,wout_b,VC*H);
  k_xt<<<dim3(S/32,(B*V)/32),dim3(32,8),0,stream>>>(x,xtb);
  k_wt<<<dim3(VC/32,G3/32),dim3(32,8),0,stream>>>(c1_Wih,WT);
  hipMemsetAsync(hf0,0,(size_t)B*H*2,stream);
  hipMemsetAsync(hb0,0,(size_t)B*H*2,stream);
  hipMemsetAsync(FE,0,16384+4*8192,stream);   // FE,F1..F4 contiguous

  EncP ep;
  ep.xtb=xtb; ep.wihf=wihf_b; ep.whhf=whhf_b; ep.wihb=wihb_b; ep.whhb=whhb_b;
  ep.bihf=gruf_bih; ep.bhhf=gruf_bhh; ep.bihb=grub_bih; ep.bhhb=grub_bhh;
  ep.hf0=hf0; ep.hf1=hf1; ep.hb0=hb0; ep.hb1=hb1;
  ep.hf=hf; ep.hb=hb; ep.FE=FE;
  k_enc<<<256,dim3(512),0,stream>>>(ep);

  k_mu_var_z<<<B,b256,0,stream>>>(hf,hb,Wmu,bmu,Wvar,bvar,noise,omu,ovar,oz,zws);
  k_zpart<<<B*G3/256,b256,0,stream>>>(zws,c1_Wih,c1_bih,zpart);
  k_h1init<<<B*H/256,b256,0,stream>>>(zws,Winit,binit,h1f,h1b0,F4);

  DecP dp;
  dp.h1b0=h1b0; dp.h1b1=h1b1; dp.h2b0=h2b0; dp.h2b1=h2b1;
  dp.w1hh=wc1hh_b; dp.w2ih=wc2ih_b; dp.w2hh=wc2hh_b; dp.wout=wout_b;
  dp.bhh1=c1_bhh; dp.bih2=c2_bih; dp.bhh2=c2_bhh; dp.bout=bout;
  dp.zpart=zpart; dp.WT=WT; dp.h1f=h1f;
  dp.logits=logits; dp.lsbuf=lsbuf; dp.recon=orecon;
  dp.F1=F1; dp.F2=F2; dp.F3=F3; dp.F4=F4;
  k_dec<<<128,dim3(512),0,stream>>>(dp);
}